// Round 8
// baseline (322.404 us; speedup 1.0000x reference)
//
#include <hip/hip_runtime.h>
#include <math.h>

#define PNUM 300000
#define B_ 2
#define D0 144
#define H0 64
#define W0 160
#define NVOX (B_*D0*H0*W0)   // 2,949,120

#define D1 72
#define H1 32
#define W1 80
#define N1S (B_*D1*H1*W1)   // 368640

#define D2 36
#define H2 16
#define W2 40
#define N2S (B_*D2*H2*W2)   // 46080

#define D3 18
#define H3 8
#define W3 20
#define N3S (B_*D3*H3*W3)   // 5760

#define D4 9
#define H4 4
#define W4 10
#define N4S (B_*D4*H4*W4)   // 720

#define EPS_ 1e-4f
#define LEAK_ 0.2f

typedef __attribute__((ext_vector_type(8))) short v8s;   // 8 bf16 (4 VGPRs)
typedef __attribute__((ext_vector_type(4))) float v4f;

typedef unsigned short ushort_t;
typedef unsigned int uint_t;
typedef unsigned long long ull_t;

__device__ __forceinline__ ushort_t f2b(float f) {
  union { float f; uint_t u; } x; x.f = f;
  uint_t r = x.u + 0x7FFFu + ((x.u >> 16) & 1u);   // RNE
  return (ushort_t)(r >> 16);
}
__device__ __forceinline__ float b2f(ushort_t h) {
  union { uint_t u; float f; } x; x.u = ((uint_t)h) << 16; return x.f;
}
// BN + LeakyReLU + mask on a packed bf16 pair
__device__ __forceinline__ uint_t bn2(uint_t w, float s0, float h0, float s1, float h1,
                                      float msk) {
  float v0 = b2f((ushort_t)(w & 0xffff));
  float v1 = b2f((ushort_t)(w >> 16));
  v0 = fmaf(v0, s0, h0); v1 = fmaf(v1, s1, h1);
  v0 = fmaxf(v0, LEAK_ * v0) * msk;    // max(v,0.2v) == LeakyReLU(0.2)
  v1 = fmaxf(v1, LEAK_ * v1) * msk;
  return (uint_t)f2b(v0) | ((uint_t)f2b(v1) << 16);
}

// workspace layout (4-byte word offsets) -- ~109 MB
#define OFF_CNT     0
#define OFF_STATS   2949120    // s1@0 q1@64 s2@128 q2@256 s3@384 q3@512 n2@641 n3@642 gcur@643 pk@644(ull: lo=k,hi=p)
#define OFF_START   2950144
#define OFF_SORTED  5899264
#define OFF_AKLIST  6199264
#define OFF_PLIST   6499264
#define OFF_WT1     6867904
#define OFF_WT2     6876096
#define OFF_WT3     6908864
#define OFF_AFEATB  6974400
#define OFF_X1B     11774400
#define OFF_X2B     23570880
#define OFF_X3B     26520000
#define OFF_M1      26888640
#define OFF_M2      27257280
#define OFF_M3      27303360

__device__ __forceinline__ int voxkey(int b, int x, int y, int z) {
  int p = ((b*D1 + (x >> 1))*H1 + (y >> 1))*W1 + (z >> 1);
  int oct = ((x & 1) << 2) | ((y & 1) << 1) | (z & 1);
  return p*8 + oct;
}

// ---------------- densify count ----------------
__global__ __launch_bounds__(256) void k_count(const int* __restrict__ coords,
                                               int* __restrict__ cnt) {
  int i = blockIdx.x * 256 + threadIdx.x;
  if (i >= PNUM) return;
  int4 c = *(const int4*)(coords + i*4);
  atomicAdd(&cnt[voxkey(c.x, c.y, c.z, c.w)], 1);
}

// ---------------- slot allocation: 1024 threads, 4096 voxels, 1 ticket/block ----------------
__global__ __launch_bounds__(1024) void k_alloc(const int* __restrict__ cnt,
                                                int* __restrict__ start,
                                                int* __restrict__ cursor,
                                                int* __restrict__ gcur) {
  __shared__ int wsum[16];
  __shared__ int blockBase;
  int t = threadIdx.x;
  int idx0 = blockIdx.x * 4096 + t * 4;
  int4 cv = *(const int4*)(cnt + idx0);
  int c0 = cv.x, c1 = cv.y, c2 = cv.z, c3 = cv.w;
  int tsum = c0 + c1 + c2 + c3;
  int lane = t & 63, wid = t >> 6;
  int incl = tsum;
#pragma unroll
  for (int off = 1; off < 64; off <<= 1) {
    int v = __shfl_up(incl, off);
    if (lane >= off) incl += v;
  }
  if (lane == 63) wsum[wid] = incl;
  __syncthreads();
  if (t == 0) {
    int tot = 0;
#pragma unroll
    for (int w = 0; w < 16; w++) { int v = wsum[w]; wsum[w] = tot; tot += v; }
    blockBase = atomicAdd(gcur, tot);
  }
  __syncthreads();
  int st = blockBase + wsum[wid] + incl - tsum;
  start[idx0 + 0] = st; cursor[idx0 + 0] = st; st += c0;
  start[idx0 + 1] = st; cursor[idx0 + 1] = st; st += c1;
  start[idx0 + 2] = st; cursor[idx0 + 2] = st; st += c2;
  start[idx0 + 3] = st; cursor[idx0 + 3] = st;
}

// ---------------- counting-sort scatter ----------------
__global__ __launch_bounds__(256) void k_scatter(const int* __restrict__ coords,
                                                 int* __restrict__ cursor,
                                                 int* __restrict__ sorted) {
  int i = blockIdx.x * 256 + threadIdx.x;
  if (i >= PNUM) return;
  int4 c = *(const int4*)(coords + i*4);
  int slot = atomicAdd(&cursor[voxkey(c.x, c.y, c.z, c.w)], 1);
  sorted[slot] = i;
}

// ---------------- compaction: 1024 threads, ONE packed 64-bit ticket per block ----------------
__global__ __launch_bounds__(1024) void k_plist(const int* __restrict__ cnt,
                                                float* __restrict__ m1,
                                                int* __restrict__ plist,
                                                int* __restrict__ aklist,
                                                ull_t* __restrict__ pkctr) {
  __shared__ int wsum[16];
  __shared__ ull_t sbase;
  int t = threadIdx.x;
  int p = blockIdx.x * 1024 + t;
  int lane = t & 63, wid = t >> 6;
  const int4* c4 = (const int4*)(cnt + (size_t)p*8);
  int4 a = c4[0], b = c4[1];
  int cn[8] = {a.x, a.y, a.z, a.w, b.x, b.y, b.z, b.w};
  int ck = 0;
#pragma unroll
  for (int i = 0; i < 8; i++) ck += (cn[i] > 0) ? 1 : 0;
  int pa = (ck > 0) ? 1 : 0;
  m1[p] = pa ? 1.f : 0.f;
  int packed = (pa << 16) | ck;
  int incl = packed;
#pragma unroll
  for (int o = 1; o < 64; o <<= 1) {
    int v = __shfl_up(incl, o);
    if (lane >= o) incl += v;
  }
  if (lane == 63) wsum[wid] = incl;
  __syncthreads();
  if (t == 0) {
    int tot = 0;
#pragma unroll
    for (int w = 0; w < 16; w++) { int v = wsum[w]; wsum[w] = tot; tot += v; }
    ull_t add = ((ull_t)(uint_t)(tot >> 16) << 32) | (ull_t)(uint_t)(tot & 0xffff);
    sbase = atomicAdd(pkctr, add);
  }
  __syncthreads();
  ull_t base = sbase;
  int excl = wsum[wid] + incl - packed;
  int poff = (int)(base >> 32) + (excl >> 16);
  int koff = (int)(base & 0xffffffffULL) + (excl & 0xffff);
  if (pa) plist[poff] = p;
#pragma unroll
  for (int i = 0; i < 8; i++)
    if (cn[i] > 0) aklist[koff++] = p*8 + i;
}

// ---------------- duplicate-averaging -> bf16 afeat (8 threads/key) ----------------
__global__ __launch_bounds__(256) void k_avg(const float* __restrict__ feat,
                                             const int* __restrict__ sorted,
                                             const int* __restrict__ cnt,
                                             const int* __restrict__ start,
                                             const int* __restrict__ aklist,
                                             const int* __restrict__ nactk,
                                             ushort_t* __restrict__ afb) {
  int gid = blockIdx.x * 256 + threadIdx.x;
  int j = gid >> 3;
  if (j >= nactk[0]) return;
  int key = aklist[j];
  int c = cnt[key];
  int s0 = start[key];
  int q = (gid & 7) * 4;
  float4 acc = {0.f, 0.f, 0.f, 0.f};
  for (int i = 0; i < c; i++) {
    float4 v = *(const float4*)(feat + (size_t)sorted[s0 + i] * 32 + q);
    acc.x += v.x; acc.y += v.y; acc.z += v.z; acc.w += v.w;
  }
  float inv = 1.f / (float)c;
  uint2 o;
  o.x = (uint_t)f2b(acc.x*inv) | ((uint_t)f2b(acc.y*inv) << 16);
  o.y = (uint_t)f2b(acc.z*inv) | ((uint_t)f2b(acc.w*inv) << 16);
  *(uint2*)(afb + (size_t)s0 * 32 + q) = o;
}

// ---------------- weight prep: bf16 + [chunk32][cout][32] layout ----------------
__global__ __launch_bounds__(256) void k_prepw(const float* __restrict__ w1,
                                               const float* __restrict__ w2,
                                               const float* __restrict__ w3,
                                               ushort_t* __restrict__ wt1,
                                               ushort_t* __restrict__ wt2,
                                               ushort_t* __restrict__ wt3) {
  int idx = blockIdx.x * 256 + threadIdx.x;
  if (idx < 16384) {
    int c = idx >> 11, r = idx & 2047;
    int co = r >> 5, kk = r & 31;
    wt1[idx] = f2b(w1[(c*32 + kk)*64 + co]);
  } else if (idx < 16384 + 65536) {
    int i = idx - 16384;
    int c = i >> 12, r = i & 4095;
    int co = r >> 5, kk = r & 31;
    int k = c*32 + kk;
    wt2[i] = (co < 96) ? f2b(w2[k*96 + co]) : 0;
  } else if (idx < 16384 + 65536 + 131072) {
    int i = idx - 81920;
    int c = i >> 12, r = i & 4095;
    int co = r >> 5, kk = r & 31;
    int k = c*32 + kk;
    int ch = k >> 7, ci = k & 127;
    wt3[i] = (ci < 96) ? f2b(w3[(ch*96 + ci)*128 + co]) : 0;
  }
}

// ---------------- MFMA conv1: barrier-free K-loop, direct global gathers ----------------
// 128 active parents x 64 couts per block; A-frag gathered from afb, B-frag from wtg
// (L1/L2-hot). No LDS staging in the K-loop -> no per-chunk vmcnt(0) barrier drain.
__global__ __launch_bounds__(256) void k_conv1m(
    const ushort_t* __restrict__ afb, const int* __restrict__ cnt,
    const int* __restrict__ start, const int* __restrict__ plist,
    const int* __restrict__ nactp, const ushort_t* __restrict__ wtg,
    ushort_t* __restrict__ x1b, float* __restrict__ sumv, float* __restrict__ sqv) {
  int nact = nactp[0];
  if (blockIdx.x * 128 >= nact) return;
  __shared__ int cst[128*8];
  __shared__ int pl[128];
  __shared__ float redS[4][64], redQ[4][64];
  int t = threadIdx.x;
  if (t < 128) {   // 1 thread = 1 parent: vectorized descriptor fetch
    int gsite = blockIdx.x * 128 + t;
    bool valid = gsite < nact;
    int p = valid ? plist[gsite] : 0;
    pl[t] = p;
    int4 c0 = {0,0,0,0}, c1 = {0,0,0,0}, s0 = {0,0,0,0}, s1 = {0,0,0,0};
    if (valid) {
      const int4* cp = (const int4*)(cnt + (size_t)p*8);
      const int4* sp = (const int4*)(start + (size_t)p*8);
      c0 = cp[0]; c1 = cp[1]; s0 = sp[0]; s1 = sp[1];
    }
    cst[t*8 + 0] = (c0.x > 0) ? s0.x : -1;
    cst[t*8 + 1] = (c0.y > 0) ? s0.y : -1;
    cst[t*8 + 2] = (c0.z > 0) ? s0.z : -1;
    cst[t*8 + 3] = (c0.w > 0) ? s0.w : -1;
    cst[t*8 + 4] = (c1.x > 0) ? s1.x : -1;
    cst[t*8 + 5] = (c1.y > 0) ? s1.y : -1;
    cst[t*8 + 6] = (c1.z > 0) ? s1.z : -1;
    cst[t*8 + 7] = (c1.w > 0) ? s1.w : -1;
  }
  __syncthreads();
  int lane = t & 63, wv = t >> 6;
  int l15 = lane & 15, q = lane >> 4;
  int SB = wv * 32;
  v4f acc[2][4];
#pragma unroll
  for (int i = 0; i < 2; i++)
#pragma unroll
    for (int j = 0; j < 4; j++) acc[i][j] = (v4f){0.f, 0.f, 0.f, 0.f};
  for (int c = 0; c < 8; c++) {
    v8s a[2], b[4];
#pragma unroll
    for (int mt = 0; mt < 2; mt++) {
      int site = SB + mt*16 + l15;
      int sp = cst[site*8 + c];
      v8s av = {0,0,0,0,0,0,0,0};
      if (sp >= 0) av = *(const v8s*)(afb + (size_t)sp*32 + q*8);
      a[mt] = av;
    }
#pragma unroll
    for (int nt = 0; nt < 4; nt++)
      b[nt] = *(const v8s*)(wtg + c*2048 + (nt*16 + l15)*32 + q*8);
#pragma unroll
    for (int mt = 0; mt < 2; mt++)
#pragma unroll
      for (int nt = 0; nt < 4; nt++)
        acc[mt][nt] = __builtin_amdgcn_mfma_f32_16x16x32_bf16(a[mt], b[nt], acc[mt][nt], 0, 0, 0);
  }
  float ss[4] = {0,0,0,0}, sq[4] = {0,0,0,0};
#pragma unroll
  for (int mt = 0; mt < 2; mt++) {
#pragma unroll
    for (int nt = 0; nt < 4; nt++) {
#pragma unroll
      for (int r = 0; r < 4; r++) {
        int sl = SB + mt*16 + q*4 + r;
        int gsite = blockIdx.x * 128 + sl;
        ushort_t h = f2b(acc[mt][nt][r]);
        float v = b2f(h);
        if (gsite < nact) x1b[(size_t)pl[sl]*64 + nt*16 + l15] = h;
        ss[nt] += v; sq[nt] += v*v;
      }
    }
  }
#pragma unroll
  for (int nt = 0; nt < 4; nt++) {
    float v1 = ss[nt], v2 = sq[nt];
    v1 += __shfl_xor(v1, 16); v1 += __shfl_xor(v1, 32);
    v2 += __shfl_xor(v2, 16); v2 += __shfl_xor(v2, 32);
    if (lane < 16) { redS[wv][nt*16 + l15] = v1; redQ[wv][nt*16 + l15] = v2; }
  }
  __syncthreads();
  if (t < 64) {
    float s = redS[0][t] + redS[1][t] + redS[2][t] + redS[3][t];
    float qq = redQ[0][t] + redQ[1][t] + redQ[2][t] + redQ[3][t];
    atomicAdd(&sumv[t], s);
    atomicAdd(&sqv[t], qq);
  }
}

// ---------------- MFMA conv (conv2/conv3): barrier-free, 64 sites x 128 couts ----------------
// A gathered from xin with BN+LeakyReLU+mask applied in registers; B from wtg (L2-hot).
template <int CSTRIDE, int CIN_REAL, bool NINT, int DO, int HO, int WO, int DP, int HP, int WP>
__global__ __launch_bounds__(256) void k_convm(
    const ushort_t* __restrict__ xin, const float* __restrict__ mprev,
    const ushort_t* __restrict__ wtg,
    const float* __restrict__ gam, const float* __restrict__ bet,
    const float* __restrict__ ssumv, const float* __restrict__ ssqv,
    const void* __restrict__ ncnt,
    ushort_t* __restrict__ xout, float* __restrict__ osum, float* __restrict__ osq) {
  const int NCHUNK = CSTRIDE / 4;          // 8*CSTRIDE / 32
  __shared__ __align__(16) float sc[CSTRIDE], sh[CSTRIDE];
  __shared__ int   cbase[64*8];
  __shared__ float cmask[64*8];
  __shared__ float redS[4][64], redQ[4][64];
  int t = threadIdx.x;
  if (t < CSTRIDE) {
    float scv = 0.f, shv = 0.f;
    if (t < CIN_REAL) {
      float n = NINT ? fmaxf((float)((const int*)ncnt)[0], 1.0f)
                     : fmaxf(((const float*)ncnt)[0], 1.0f);
      float mean = ssumv[t] / n;
      float var = ssqv[t] / n - mean * mean;
      float s = gam[t] * rsqrtf(var + EPS_);
      scv = s; shv = bet[t] - mean * s;
    }
    sc[t] = scv; sh[t] = shv;
  }
#pragma unroll
  for (int ii = 0; ii < 2; ii++) {
    int idx = t + ii*256;
    int s = idx >> 3, ch = idx & 7;
    int g = blockIdx.x * 64 + s;
    int b = g / (DO*HO*WO); int r = g - b*(DO*HO*WO);
    int ox = r / (HO*WO); r -= ox*(HO*WO);
    int oy = r / WO; int oz = r - oy*WO;
    int ps = ((b*DP + 2*ox + ((ch >> 2) & 1))*HP + 2*oy + ((ch >> 1) & 1))*WP + 2*oz + (ch & 1);
    cbase[idx] = ps * CSTRIDE;
    cmask[idx] = mprev[ps];
  }
  __syncthreads();
  int lane = t & 63, wv = t >> 6;
  int l15 = lane & 15, q = lane >> 4;
  int SB = (wv & 1) * 32, NB = (wv >> 1) * 64;
  v4f acc[2][4];
#pragma unroll
  for (int i = 0; i < 2; i++)
#pragma unroll
    for (int j = 0; j < 4; j++) acc[i][j] = (v4f){0.f, 0.f, 0.f, 0.f};
  for (int c = 0; c < NCHUNK; c++) {
    int ch = (c * 32) / CSTRIDE;
    int cio = (c * 32) % CSTRIDE + q * 8;
    float4 sc0 = *(const float4*)&sc[cio];
    float4 sc1 = *(const float4*)&sc[cio + 4];
    float4 sh0 = *(const float4*)&sh[cio];
    float4 sh1 = *(const float4*)&sh[cio + 4];
    v8s a[2], b[4];
#pragma unroll
    for (int mt = 0; mt < 2; mt++) {
      int site = SB + mt*16 + l15;
      uint4 u = *(const uint4*)(xin + (size_t)cbase[site*8 + ch] + cio);
      float msk = cmask[site*8 + ch];
      int4 pk;
      pk.x = (int)bn2(u.x, sc0.x, sh0.x, sc0.y, sh0.y, msk);
      pk.y = (int)bn2(u.y, sc0.z, sh0.z, sc0.w, sh0.w, msk);
      pk.z = (int)bn2(u.z, sc1.x, sh1.x, sc1.y, sh1.y, msk);
      pk.w = (int)bn2(u.w, sc1.z, sh1.z, sc1.w, sh1.w, msk);
      a[mt] = *(v8s*)&pk;
    }
#pragma unroll
    for (int nt = 0; nt < 4; nt++)
      b[nt] = *(const v8s*)(wtg + (size_t)c*4096 + (NB + nt*16 + l15)*32 + q*8);
#pragma unroll
    for (int mt = 0; mt < 2; mt++)
#pragma unroll
      for (int nt = 0; nt < 4; nt++)
        acc[mt][nt] = __builtin_amdgcn_mfma_f32_16x16x32_bf16(a[mt], b[nt], acc[mt][nt], 0, 0, 0);
  }
  float ss[4] = {0,0,0,0}, sq[4] = {0,0,0,0};
#pragma unroll
  for (int mt = 0; mt < 2; mt++) {
#pragma unroll
    for (int nt = 0; nt < 4; nt++) {
#pragma unroll
      for (int r = 0; r < 4; r++) {
        int sl = SB + mt*16 + q*4 + r;
        size_t gsite = (size_t)blockIdx.x * 64 + sl;
        ushort_t h = f2b(acc[mt][nt][r]);
        float v = b2f(h);
        xout[gsite*128 + NB + nt*16 + l15] = h;
        ss[nt] += v; sq[nt] += v*v;
      }
    }
  }
#pragma unroll
  for (int nt = 0; nt < 4; nt++) {
    float v1 = ss[nt], v2 = sq[nt];
    v1 += __shfl_xor(v1, 16); v1 += __shfl_xor(v1, 32);
    v2 += __shfl_xor(v2, 16); v2 += __shfl_xor(v2, 32);
    if (lane < 16) { redS[wv][nt*16 + l15] = v1; redQ[wv][nt*16 + l15] = v2; }
  }
  __syncthreads();
  if (t < 128) {
    float s, qq;
    if (t < 64) { s = redS[0][t] + redS[1][t]; qq = redQ[0][t] + redQ[1][t]; }
    else        { s = redS[2][t-64] + redS[3][t-64]; qq = redQ[2][t-64] + redQ[3][t-64]; }
    atomicAdd(&osum[t], s);
    atomicAdd(&osq[t], qq);
  }
}

// ---------------- mask downsample (+ active count, 1 atomic/block) ----------------
template <int DO, int HO, int WO, int DP, int HP, int WP>
__global__ __launch_bounds__(256) void k_mask(const float* __restrict__ prev,
                                              float* __restrict__ mout,
                                              float* __restrict__ nout, int nsites) {
  __shared__ int cw[4];
  int s = blockIdx.x * 256 + threadIdx.x;
  bool act = false;
  if (s < nsites) {
    int b = s / (DO*HO*WO); int r = s - b*(DO*HO*WO);
    int ox = r / (HO*WO); r -= ox*(HO*WO);
    int oy = r / WO; int oz = r - oy*WO;
    int base = ((b*DP + 2*ox)*HP + 2*oy)*WP + 2*oz;
#pragma unroll
    for (int ch = 0; ch < 8; ch++) {
      int idx = base + ((ch >> 2) & 1)*HP*WP + ((ch >> 1) & 1)*WP + (ch & 1);
      act |= (prev[idx] > 0.0f);
    }
    mout[s] = act ? 1.0f : 0.0f;
  }
  unsigned long long bal = __ballot(act);
  if ((threadIdx.x & 63) == 0) cw[threadIdx.x >> 6] = __popcll(bal);
  __syncthreads();
  if (threadIdx.x == 0)
    atomicAdd(nout, (float)(cw[0] + cw[1] + cw[2] + cw[3]));
}

// ---------------- final conv (cout=1) + sigmoid + mask ----------------
__global__ __launch_bounds__(256) void k_final(
    const ushort_t* __restrict__ x3b, const float* __restrict__ m3,
    const float* __restrict__ w4, const float* __restrict__ gam,
    const float* __restrict__ bet, const float* __restrict__ ssumv,
    const float* __restrict__ ssqv, const float* __restrict__ ncnt,
    float* __restrict__ out) {
  __shared__ float sc[128], sh[128];
  __shared__ int cb[8];
  __shared__ float msk[8];
  __shared__ float red[256];
  int t = threadIdx.x;
  if (t < 128) {
    float n = fmaxf(ncnt[0], 1.0f);
    float mean = ssumv[t] / n;
    float var = ssqv[t] / n - mean * mean;
    float s = gam[t] * rsqrtf(var + EPS_);
    sc[t] = s; sh[t] = bet[t] - mean * s;
  }
  int g = blockIdx.x;
  int b = g / (D4*H4*W4); int r = g - b*(D4*H4*W4);
  int ox = r / (H4*W4); r -= ox*(H4*W4);
  int oy = r / W4; int oz = r - oy*W4;
  if (t < 8) {
    int ps = ((b*D3 + 2*ox + ((t >> 2) & 1))*H3 + 2*oy + ((t >> 1) & 1))*W3 + 2*oz + (t & 1);
    cb[t] = ps * 128;
    msk[t] = m3[ps];
  }
  __syncthreads();
  float acc = 0.f;
#pragma unroll
  for (int ii = 0; ii < 4; ii++) {
    int k = t + ii*256;
    int ch = k >> 7, ci = k & 127;
    float v = b2f(x3b[cb[ch] + ci]);
    v = v * sc[ci] + sh[ci];
    v = (v > 0.f ? v : LEAK_ * v) * msk[ch];
    acc += v * w4[k];
  }
  red[t] = acc;
  __syncthreads();
  if (t < 128) red[t] += red[t + 128];
  __syncthreads();
  if (t < 64) {
    float v = red[t] + red[t + 64];
#pragma unroll
    for (int off = 32; off > 0; off >>= 1) v += __shfl_down(v, off);
    if (t == 0) {
      float any = (msk[0] + msk[1] + msk[2] + msk[3] + msk[4] + msk[5] + msk[6] + msk[7]) > 0.f ? 1.f : 0.f;
      out[g] = any / (1.0f + expf(-v));
    }
  }
}

extern "C" void kernel_launch(void* const* d_in, const int* in_sizes, int n_in,
                              void* d_out, int out_size, void* d_ws, size_t ws_size,
                              hipStream_t stream) {
  (void)in_sizes; (void)n_in; (void)out_size; (void)ws_size;
  const float* feat = (const float*)d_in[0];
  const int*   crd  = (const int*)d_in[1];
  const float* w1 = (const float*)d_in[2];
  const float* g1 = (const float*)d_in[3];
  const float* b1 = (const float*)d_in[4];
  const float* w2 = (const float*)d_in[5];
  const float* g2 = (const float*)d_in[6];
  const float* b2 = (const float*)d_in[7];
  const float* w3 = (const float*)d_in[8];
  const float* g3 = (const float*)d_in[9];
  const float* b3 = (const float*)d_in[10];
  const float* w4 = (const float*)d_in[11];
  float* out = (float*)d_out;
  float* ws  = (float*)d_ws;

  int*      cnt    = (int*)(ws + OFF_CNT);
  float*    st     = ws + OFF_STATS;
  int*      start  = (int*)(ws + OFF_START);
  int*      sorted = (int*)(ws + OFF_SORTED);
  int*      aklist = (int*)(ws + OFF_AKLIST);
  int*      plist  = (int*)(ws + OFF_PLIST);
  ushort_t* wt1g   = (ushort_t*)(ws + OFF_WT1);
  ushort_t* wt2g   = (ushort_t*)(ws + OFF_WT2);
  ushort_t* wt3g   = (ushort_t*)(ws + OFF_WT3);
  ushort_t* afb    = (ushort_t*)(ws + OFF_AFEATB);
  ushort_t* x1b    = (ushort_t*)(ws + OFF_X1B);
  int*      cursor = (int*)(ws + OFF_X1B);   // overlays x1b head; dead after k_scatter
  ushort_t* x2b    = (ushort_t*)(ws + OFF_X2B);
  ushort_t* x3b    = (ushort_t*)(ws + OFF_X3B);
  float*    m1     = ws + OFF_M1;
  float*    m2     = ws + OFF_M2;
  float*    m3     = ws + OFF_M3;
  ull_t*    pkctr  = (ull_t*)(st + 644);
  int*      nactk  = (int*)(st + 644);
  int*      nactp  = (int*)(st + 645);

  hipMemsetAsync(d_ws, 0, (size_t)(OFF_STATS + 1024) * sizeof(float), stream);

  k_count<<<(PNUM + 255) / 256, 256, 0, stream>>>(crd, cnt);
  k_alloc<<<NVOX / 4096, 1024, 0, stream>>>(cnt, start, cursor, (int*)(st + 643));
  k_scatter<<<(PNUM + 255) / 256, 256, 0, stream>>>(crd, cursor, sorted);
  k_plist<<<N1S / 1024, 1024, 0, stream>>>(cnt, m1, plist, aklist, pkctr);
  k_avg<<<(PNUM * 8) / 256 + 1, 256, 0, stream>>>(feat, sorted, cnt, start, aklist,
                                                  nactk, afb);
  k_prepw<<<(16384 + 65536 + 131072) / 256, 256, 0, stream>>>(w1, w2, w3, wt1g, wt2g, wt3g);
  hipMemsetAsync(x1b, 0, (size_t)N1S * 64 * sizeof(ushort_t), stream);
  k_conv1m<<<N1S / 128, 256, 0, stream>>>(afb, cnt, start, plist,
                                          nactp, wt1g, x1b, st + 0, st + 64);
  k_mask<D2,H2,W2, D1,H1,W1><<<N2S / 256, 256, 0, stream>>>(m1, m2, st + 641, N2S);
  k_convm<64, 64, true, D2,H2,W2, D1,H1,W1><<<N2S / 64, 256, 0, stream>>>(
      x1b, m1, wt2g, g1, b1, st + 0, st + 64, (const void*)nactp, x2b, st + 128, st + 256);
  k_mask<D3,H3,W3, D2,H2,W2><<<(N3S + 255) / 256, 256, 0, stream>>>(m2, m3, st + 642, N3S);
  k_convm<128, 96, false, D3,H3,W3, D2,H2,W2><<<N3S / 64, 256, 0, stream>>>(
      x2b, m2, wt3g, g2, b2, st + 128, st + 256, (const void*)(st + 641), x3b, st + 384, st + 512);
  k_final<<<N4S, 256, 0, stream>>>(x3b, m3, w4, g3, b3, st + 384, st + 512, st + 642, out);
}

// Round 9
// 315.850 us; speedup vs baseline: 1.0208x; 1.0208x over previous
//
#include <hip/hip_runtime.h>
#include <math.h>

#define PNUM 300000
#define B_ 2
#define D0 144
#define H0 64
#define W0 160
#define NVOX (B_*D0*H0*W0)   // 2,949,120

#define D1 72
#define H1 32
#define W1 80
#define N1S (B_*D1*H1*W1)   // 368640

#define D2 36
#define H2 16
#define W2 40
#define N2S (B_*D2*H2*W2)   // 46080

#define D3 18
#define H3 8
#define W3 20
#define N3S (B_*D3*H3*W3)   // 5760

#define D4 9
#define H4 4
#define W4 10
#define N4S (B_*D4*H4*W4)   // 720

#define EPS_ 1e-4f
#define LEAK_ 0.2f

typedef __attribute__((ext_vector_type(8))) short v8s;   // 8 bf16 (4 VGPRs)
typedef __attribute__((ext_vector_type(4))) float v4f;

typedef unsigned short ushort_t;
typedef unsigned int uint_t;
typedef unsigned long long ull_t;

__device__ __forceinline__ ushort_t f2b(float f) {
  union { float f; uint_t u; } x; x.f = f;
  uint_t r = x.u + 0x7FFFu + ((x.u >> 16) & 1u);   // RNE
  return (ushort_t)(r >> 16);
}
__device__ __forceinline__ float b2f(ushort_t h) {
  union { uint_t u; float f; } x; x.u = ((uint_t)h) << 16; return x.f;
}
__device__ __forceinline__ uint_t bn2(uint_t w, float s0, float h0, float s1, float h1,
                                      float msk) {
  float v0 = b2f((ushort_t)(w & 0xffff));
  float v1 = b2f((ushort_t)(w >> 16));
  v0 = fmaf(v0, s0, h0); v1 = fmaf(v1, s1, h1);
  v0 = fmaxf(v0, LEAK_ * v0) * msk;
  v1 = fmaxf(v1, LEAK_ * v1) * msk;
  return (uint_t)f2b(v0) | ((uint_t)f2b(v1) << 16);
}

// workspace layout (4-byte word offsets) -- ~109 MB
#define OFF_CNT     0
#define OFF_STATS   2949120    // s1@0 q1@64 s2@128 q2@256 s3@384 q3@512 n2@641 n3@642 gcur@643 pk@644(ull: lo=k,hi=p)
#define OFF_START   2950144
#define OFF_SORTED  5899264
#define OFF_AKLIST  6199264
#define OFF_PLIST   6499264
#define OFF_WT1     6867904
#define OFF_WT2     6876096
#define OFF_WT3     6908864
#define OFF_AFEATB  6974400
#define OFF_X1B     11774400
#define OFF_X2B     23570880
#define OFF_X3B     26520000
#define OFF_M1      26888640
#define OFF_M2      27257280
#define OFF_M3      27303360

__device__ __forceinline__ int voxkey(int b, int x, int y, int z) {
  int p = ((b*D1 + (x >> 1))*H1 + (y >> 1))*W1 + (z >> 1);
  int oct = ((x & 1) << 2) | ((y & 1) << 1) | (z & 1);
  return p*8 + oct;
}

// ---------------- densify count ----------------
__global__ __launch_bounds__(256) void k_count(const int* __restrict__ coords,
                                               int* __restrict__ cnt) {
  int i = blockIdx.x * 256 + threadIdx.x;
  if (i >= PNUM) return;
  int4 c = *(const int4*)(coords + i*4);
  atomicAdd(&cnt[voxkey(c.x, c.y, c.z, c.w)], 1);
}

// ---------------- slot allocation: 1024 threads, 4096 voxels, 1 ticket/block ----------------
__global__ __launch_bounds__(1024) void k_alloc(const int* __restrict__ cnt,
                                                int* __restrict__ start,
                                                int* __restrict__ cursor,
                                                int* __restrict__ gcur) {
  __shared__ int wsum[16];
  __shared__ int blockBase;
  int t = threadIdx.x;
  int idx0 = blockIdx.x * 4096 + t * 4;
  int4 cv = *(const int4*)(cnt + idx0);
  int c0 = cv.x, c1 = cv.y, c2 = cv.z, c3 = cv.w;
  int tsum = c0 + c1 + c2 + c3;
  int lane = t & 63, wid = t >> 6;
  int incl = tsum;
#pragma unroll
  for (int off = 1; off < 64; off <<= 1) {
    int v = __shfl_up(incl, off);
    if (lane >= off) incl += v;
  }
  if (lane == 63) wsum[wid] = incl;
  __syncthreads();
  if (t == 0) {
    int tot = 0;
#pragma unroll
    for (int w = 0; w < 16; w++) { int v = wsum[w]; wsum[w] = tot; tot += v; }
    blockBase = atomicAdd(gcur, tot);
  }
  __syncthreads();
  int st = blockBase + wsum[wid] + incl - tsum;
  start[idx0 + 0] = st; cursor[idx0 + 0] = st; st += c0;
  start[idx0 + 1] = st; cursor[idx0 + 1] = st; st += c1;
  start[idx0 + 2] = st; cursor[idx0 + 2] = st; st += c2;
  start[idx0 + 3] = st; cursor[idx0 + 3] = st;
}

// ---------------- counting-sort scatter ----------------
__global__ __launch_bounds__(256) void k_scatter(const int* __restrict__ coords,
                                                 int* __restrict__ cursor,
                                                 int* __restrict__ sorted) {
  int i = blockIdx.x * 256 + threadIdx.x;
  if (i >= PNUM) return;
  int4 c = *(const int4*)(coords + i*4);
  int slot = atomicAdd(&cursor[voxkey(c.x, c.y, c.z, c.w)], 1);
  sorted[slot] = i;
}

// ---------------- compaction: m1 + aklist + packed ticket ----------------
__global__ __launch_bounds__(1024) void k_plist(const int* __restrict__ cnt,
                                                float* __restrict__ m1,
                                                int* __restrict__ plist,
                                                int* __restrict__ aklist,
                                                ull_t* __restrict__ pkctr) {
  __shared__ int wsum[16];
  __shared__ ull_t sbase;
  int t = threadIdx.x;
  int p = blockIdx.x * 1024 + t;
  int lane = t & 63, wid = t >> 6;
  const int4* c4 = (const int4*)(cnt + (size_t)p*8);
  int4 a = c4[0], b = c4[1];
  int cn[8] = {a.x, a.y, a.z, a.w, b.x, b.y, b.z, b.w};
  int ck = 0;
#pragma unroll
  for (int i = 0; i < 8; i++) ck += (cn[i] > 0) ? 1 : 0;
  int pa = (ck > 0) ? 1 : 0;
  m1[p] = pa ? 1.f : 0.f;
  int packed = (pa << 16) | ck;
  int incl = packed;
#pragma unroll
  for (int o = 1; o < 64; o <<= 1) {
    int v = __shfl_up(incl, o);
    if (lane >= o) incl += v;
  }
  if (lane == 63) wsum[wid] = incl;
  __syncthreads();
  if (t == 0) {
    int tot = 0;
#pragma unroll
    for (int w = 0; w < 16; w++) { int v = wsum[w]; wsum[w] = tot; tot += v; }
    ull_t add = ((ull_t)(uint_t)(tot >> 16) << 32) | (ull_t)(uint_t)(tot & 0xffff);
    sbase = atomicAdd(pkctr, add);
  }
  __syncthreads();
  ull_t base = sbase;
  int excl = wsum[wid] + incl - packed;
  int poff = (int)(base >> 32) + (excl >> 16);
  int koff = (int)(base & 0xffffffffULL) + (excl & 0xffff);
  if (pa) plist[poff] = p;
#pragma unroll
  for (int i = 0; i < 8; i++)
    if (cn[i] > 0) aklist[koff++] = p*8 + i;
}

// ---------------- duplicate-averaging -> bf16 afeat (8 threads/key) ----------------
__global__ __launch_bounds__(256) void k_avg(const float* __restrict__ feat,
                                             const int* __restrict__ sorted,
                                             const int* __restrict__ cnt,
                                             const int* __restrict__ start,
                                             const int* __restrict__ aklist,
                                             const int* __restrict__ nactk,
                                             ushort_t* __restrict__ afb) {
  int gid = blockIdx.x * 256 + threadIdx.x;
  int j = gid >> 3;
  if (j >= nactk[0]) return;
  int key = aklist[j];
  int c = cnt[key];
  int s0 = start[key];
  int q = (gid & 7) * 4;
  float4 acc = {0.f, 0.f, 0.f, 0.f};
  for (int i = 0; i < c; i++) {
    float4 v = *(const float4*)(feat + (size_t)sorted[s0 + i] * 32 + q);
    acc.x += v.x; acc.y += v.y; acc.z += v.z; acc.w += v.w;
  }
  float inv = 1.f / (float)c;
  uint2 o;
  o.x = (uint_t)f2b(acc.x*inv) | ((uint_t)f2b(acc.y*inv) << 16);
  o.y = (uint_t)f2b(acc.z*inv) | ((uint_t)f2b(acc.w*inv) << 16);
  *(uint2*)(afb + (size_t)s0 * 32 + q) = o;
}

// ---------------- weight prep: bf16 + [chunk32][cout][32] layout ----------------
__global__ __launch_bounds__(256) void k_prepw(const float* __restrict__ w1,
                                               const float* __restrict__ w2,
                                               const float* __restrict__ w3,
                                               ushort_t* __restrict__ wt1,
                                               ushort_t* __restrict__ wt2,
                                               ushort_t* __restrict__ wt3) {
  int idx = blockIdx.x * 256 + threadIdx.x;
  if (idx < 16384) {
    int c = idx >> 11, r = idx & 2047;
    int co = r >> 5, kk = r & 31;
    wt1[idx] = f2b(w1[(c*32 + kk)*64 + co]);
  } else if (idx < 16384 + 65536) {
    int i = idx - 16384;
    int c = i >> 12, r = i & 4095;
    int co = r >> 5, kk = r & 31;
    int k = c*32 + kk;
    wt2[i] = (co < 96) ? f2b(w2[k*96 + co]) : 0;
  } else if (idx < 16384 + 65536 + 131072) {
    int i = idx - 81920;
    int c = i >> 12, r = i & 4095;
    int co = r >> 5, kk = r & 31;
    int k = c*32 + kk;
    int ch = k >> 7, ci = k & 127;
    wt3[i] = (ci < 96) ? f2b(w3[(ch*96 + ci)*128 + co]) : 0;
  }
}

// ---------------- MFMA conv1: full grid, all A-frags preloaded (max MLP) ----------------
// 128 parents x 64 couts per block; ALL 16 A-gathers issued up-front into registers
// (no per-chunk vmcnt drain); weights in 32 KB LDS; coalesced stores over all parents
// (zeros at inactive) -> no x1b memset needed.
__global__ __launch_bounds__(256) void k_conv1m(
    const ushort_t* __restrict__ afb, const int* __restrict__ cnt,
    const int* __restrict__ start, const ushort_t* __restrict__ wtg,
    ushort_t* __restrict__ x1b, float* __restrict__ sumv, float* __restrict__ sqv) {
  __shared__ __align__(16) ushort_t wlds[16384];   // 32 KB: all of wt1
  __shared__ int cst[128*9];
  __shared__ float redS[4][64], redQ[4][64];
  int t = threadIdx.x;
#pragma unroll
  for (int i = 0; i < 8; i++)
    ((uint4*)wlds)[t + i*256] = ((const uint4*)wtg)[t + i*256];
  if (t < 128) {
    int p = blockIdx.x * 128 + t;
    const int4* cp = (const int4*)(cnt + (size_t)p*8);
    const int4* sp = (const int4*)(start + (size_t)p*8);
    int4 c0 = cp[0], c1 = cp[1], s0 = sp[0], s1 = sp[1];
    cst[t*9 + 0] = (c0.x > 0) ? s0.x : -1;
    cst[t*9 + 1] = (c0.y > 0) ? s0.y : -1;
    cst[t*9 + 2] = (c0.z > 0) ? s0.z : -1;
    cst[t*9 + 3] = (c0.w > 0) ? s0.w : -1;
    cst[t*9 + 4] = (c1.x > 0) ? s1.x : -1;
    cst[t*9 + 5] = (c1.y > 0) ? s1.y : -1;
    cst[t*9 + 6] = (c1.z > 0) ? s1.z : -1;
    cst[t*9 + 7] = (c1.w > 0) ? s1.w : -1;
  }
  __syncthreads();
  int lane = t & 63, wv = t >> 6;
  int l15 = lane & 15, q = lane >> 4;
  int SB = wv * 32;
  // preload ALL A-fragments: 16 independent gathers in flight
  v8s a[8][2];
#pragma unroll
  for (int c = 0; c < 8; c++) {
#pragma unroll
    for (int mt = 0; mt < 2; mt++) {
      int site = SB + mt*16 + l15;
      int sp = cst[site*9 + c];
      v8s av = {0,0,0,0,0,0,0,0};
      if (sp >= 0) av = *(const v8s*)(afb + (size_t)sp*32 + q*8);
      a[c][mt] = av;
    }
  }
  v4f acc[2][4];
#pragma unroll
  for (int i = 0; i < 2; i++)
#pragma unroll
    for (int j = 0; j < 4; j++) acc[i][j] = (v4f){0.f, 0.f, 0.f, 0.f};
#pragma unroll
  for (int c = 0; c < 8; c++) {
    v8s b[4];
#pragma unroll
    for (int nt = 0; nt < 4; nt++)
      b[nt] = *(const v8s*)&wlds[c*2048 + (nt*16 + l15)*32 + q*8];
#pragma unroll
    for (int mt = 0; mt < 2; mt++)
#pragma unroll
      for (int nt = 0; nt < 4; nt++)
        acc[mt][nt] = __builtin_amdgcn_mfma_f32_16x16x32_bf16(a[c][mt], b[nt], acc[mt][nt], 0, 0, 0);
  }
  int pbase = blockIdx.x * 128;
  float ss[4] = {0,0,0,0}, sq[4] = {0,0,0,0};
#pragma unroll
  for (int mt = 0; mt < 2; mt++) {
#pragma unroll
    for (int nt = 0; nt < 4; nt++) {
#pragma unroll
      for (int r = 0; r < 4; r++) {
        int sl = SB + mt*16 + q*4 + r;
        ushort_t h = f2b(acc[mt][nt][r]);
        float v = b2f(h);
        x1b[(size_t)(pbase + sl)*64 + nt*16 + l15] = h;
        ss[nt] += v; sq[nt] += v*v;
      }
    }
  }
#pragma unroll
  for (int nt = 0; nt < 4; nt++) {
    float v1 = ss[nt], v2 = sq[nt];
    v1 += __shfl_xor(v1, 16); v1 += __shfl_xor(v1, 32);
    v2 += __shfl_xor(v2, 16); v2 += __shfl_xor(v2, 32);
    if (lane < 16) { redS[wv][nt*16 + l15] = v1; redQ[wv][nt*16 + l15] = v2; }
  }
  __syncthreads();
  if (t < 64) {
    float s = redS[0][t] + redS[1][t] + redS[2][t] + redS[3][t];
    float qq = redQ[0][t] + redQ[1][t] + redQ[2][t] + redQ[3][t];
    atomicAdd(&sumv[t], s);
    atomicAdd(&sqv[t], qq);
  }
}

// ---------------- MFMA conv (conv2/conv3): 2-deep A/B register pipeline ----------------
// 64 sites x 128 couts; fused input BN+LeakyReLU+mask; fused OUTPUT mask+count epilogue.
template <int CSTRIDE, int CIN_REAL, bool NINT, int DO, int HO, int WO, int DP, int HP, int WP>
__global__ __launch_bounds__(256) void k_convm(
    const ushort_t* __restrict__ xin, const float* __restrict__ mprev,
    const ushort_t* __restrict__ wtg,
    const float* __restrict__ gam, const float* __restrict__ bet,
    const float* __restrict__ ssumv, const float* __restrict__ ssqv,
    const void* __restrict__ ncnt,
    ushort_t* __restrict__ xout, float* __restrict__ osum, float* __restrict__ osq,
    float* __restrict__ mout, float* __restrict__ nout) {
  const int NCHUNK = CSTRIDE / 4;
  __shared__ __align__(16) float sc[CSTRIDE], sh[CSTRIDE];
  __shared__ int   cbase[64*9];
  __shared__ float cmask[64*9];
  __shared__ float redS[4][64], redQ[4][64];
  int t = threadIdx.x;
  if (t < CSTRIDE) {
    float scv = 0.f, shv = 0.f;
    if (t < CIN_REAL) {
      float n = NINT ? fmaxf((float)((const int*)ncnt)[0], 1.0f)
                     : fmaxf(((const float*)ncnt)[0], 1.0f);
      float mean = ssumv[t] / n;
      float var = ssqv[t] / n - mean * mean;
      float s = gam[t] * rsqrtf(var + EPS_);
      scv = s; shv = bet[t] - mean * s;
    }
    sc[t] = scv; sh[t] = shv;
  }
#pragma unroll
  for (int ii = 0; ii < 2; ii++) {
    int idx = t + ii*256;
    int s = idx >> 3, ch = idx & 7;
    int g = blockIdx.x * 64 + s;
    int b = g / (DO*HO*WO); int r = g - b*(DO*HO*WO);
    int ox = r / (HO*WO); r -= ox*(HO*WO);
    int oy = r / WO; int oz = r - oy*WO;
    int ps = ((b*DP + 2*ox + ((ch >> 2) & 1))*HP + 2*oy + ((ch >> 1) & 1))*WP + 2*oz + (ch & 1);
    cbase[s*9 + ch] = ps * CSTRIDE;
    cmask[s*9 + ch] = mprev[ps];
  }
  __syncthreads();
  int lane = t & 63, wv = t >> 6;
  int l15 = lane & 15, q = lane >> 4;
  int SB = (wv & 1) * 32, NB = (wv >> 1) * 64;
  v4f acc[2][4];
#pragma unroll
  for (int i = 0; i < 2; i++)
#pragma unroll
    for (int j = 0; j < 4; j++) acc[i][j] = (v4f){0.f, 0.f, 0.f, 0.f};
  uint4 rawN[2]; float mskN[2]; v8s bN[4];
#pragma unroll
  for (int mt = 0; mt < 2; mt++) {
    int site = SB + mt*16 + l15;
    rawN[mt] = *(const uint4*)(xin + (size_t)cbase[site*9] + q*8);
    mskN[mt] = cmask[site*9];
  }
#pragma unroll
  for (int nt = 0; nt < 4; nt++)
    bN[nt] = *(const v8s*)(wtg + (NB + nt*16 + l15)*32 + q*8);
#pragma unroll
  for (int c = 0; c < NCHUNK; c++) {
    uint4 raw[2] = {rawN[0], rawN[1]};
    float mskc[2] = {mskN[0], mskN[1]};
    v8s b[4] = {bN[0], bN[1], bN[2], bN[3]};
    if (c + 1 < NCHUNK) {
      int ch1 = ((c+1) * 32) / CSTRIDE;
      int cio1 = ((c+1) * 32) % CSTRIDE + q * 8;
#pragma unroll
      for (int mt = 0; mt < 2; mt++) {
        int site = SB + mt*16 + l15;
        rawN[mt] = *(const uint4*)(xin + (size_t)cbase[site*9 + ch1] + cio1);
        mskN[mt] = cmask[site*9 + ch1];
      }
#pragma unroll
      for (int nt = 0; nt < 4; nt++)
        bN[nt] = *(const v8s*)(wtg + (size_t)(c+1)*4096 + (NB + nt*16 + l15)*32 + q*8);
    }
    int cio = (c * 32) % CSTRIDE + q * 8;
    float4 sc0 = *(const float4*)&sc[cio];
    float4 sc1 = *(const float4*)&sc[cio + 4];
    float4 sh0 = *(const float4*)&sh[cio];
    float4 sh1 = *(const float4*)&sh[cio + 4];
    v8s a[2];
#pragma unroll
    for (int mt = 0; mt < 2; mt++) {
      int4 pk;
      pk.x = (int)bn2(raw[mt].x, sc0.x, sh0.x, sc0.y, sh0.y, mskc[mt]);
      pk.y = (int)bn2(raw[mt].y, sc0.z, sh0.z, sc0.w, sh0.w, mskc[mt]);
      pk.z = (int)bn2(raw[mt].z, sc1.x, sh1.x, sc1.y, sh1.y, mskc[mt]);
      pk.w = (int)bn2(raw[mt].w, sc1.z, sh1.z, sc1.w, sh1.w, mskc[mt]);
      a[mt] = *(v8s*)&pk;
    }
#pragma unroll
    for (int mt = 0; mt < 2; mt++)
#pragma unroll
      for (int nt = 0; nt < 4; nt++)
        acc[mt][nt] = __builtin_amdgcn_mfma_f32_16x16x32_bf16(a[mt], b[nt], acc[mt][nt], 0, 0, 0);
  }
  float ss[4] = {0,0,0,0}, sq[4] = {0,0,0,0};
#pragma unroll
  for (int mt = 0; mt < 2; mt++) {
#pragma unroll
    for (int nt = 0; nt < 4; nt++) {
#pragma unroll
      for (int r = 0; r < 4; r++) {
        int sl = SB + mt*16 + q*4 + r;
        size_t gsite = (size_t)blockIdx.x * 64 + sl;
        ushort_t h = f2b(acc[mt][nt][r]);
        float v = b2f(h);
        xout[gsite*128 + NB + nt*16 + l15] = h;
        ss[nt] += v; sq[nt] += v*v;
      }
    }
  }
  // fused output-mask epilogue (replaces k_mask dispatch)
  if (t < 64) {
    bool act = false;
#pragma unroll
    for (int ch = 0; ch < 8; ch++) act |= (cmask[t*9 + ch] > 0.f);
    mout[blockIdx.x * 64 + t] = act ? 1.f : 0.f;
    unsigned long long bal = __ballot(act);
    if (t == 0) atomicAdd(nout, (float)__popcll(bal));
  }
#pragma unroll
  for (int nt = 0; nt < 4; nt++) {
    float v1 = ss[nt], v2 = sq[nt];
    v1 += __shfl_xor(v1, 16); v1 += __shfl_xor(v1, 32);
    v2 += __shfl_xor(v2, 16); v2 += __shfl_xor(v2, 32);
    if (lane < 16) { redS[wv][nt*16 + l15] = v1; redQ[wv][nt*16 + l15] = v2; }
  }
  __syncthreads();
  if (t < 128) {
    float s, qq;
    if (t < 64) { s = redS[0][t] + redS[1][t]; qq = redQ[0][t] + redQ[1][t]; }
    else        { s = redS[2][t-64] + redS[3][t-64]; qq = redQ[2][t-64] + redQ[3][t-64]; }
    atomicAdd(&osum[t], s);
    atomicAdd(&osq[t], qq);
  }
}

// ---------------- final conv (cout=1) + sigmoid + mask ----------------
__global__ __launch_bounds__(256) void k_final(
    const ushort_t* __restrict__ x3b, const float* __restrict__ m3,
    const float* __restrict__ w4, const float* __restrict__ gam,
    const float* __restrict__ bet, const float* __restrict__ ssumv,
    const float* __restrict__ ssqv, const float* __restrict__ ncnt,
    float* __restrict__ out) {
  __shared__ float sc[128], sh[128];
  __shared__ int cb[8];
  __shared__ float msk[8];
  __shared__ float red[256];
  int t = threadIdx.x;
  if (t < 128) {
    float n = fmaxf(ncnt[0], 1.0f);
    float mean = ssumv[t] / n;
    float var = ssqv[t] / n - mean * mean;
    float s = gam[t] * rsqrtf(var + EPS_);
    sc[t] = s; sh[t] = bet[t] - mean * s;
  }
  int g = blockIdx.x;
  int b = g / (D4*H4*W4); int r = g - b*(D4*H4*W4);
  int ox = r / (H4*W4); r -= ox*(H4*W4);
  int oy = r / W4; int oz = r - oy*W4;
  if (t < 8) {
    int ps = ((b*D3 + 2*ox + ((t >> 2) & 1))*H3 + 2*oy + ((t >> 1) & 1))*W3 + 2*oz + (t & 1);
    cb[t] = ps * 128;
    msk[t] = m3[ps];
  }
  __syncthreads();
  float acc = 0.f;
#pragma unroll
  for (int ii = 0; ii < 4; ii++) {
    int k = t + ii*256;
    int ch = k >> 7, ci = k & 127;
    float v = b2f(x3b[cb[ch] + ci]);
    v = v * sc[ci] + sh[ci];
    v = (v > 0.f ? v : LEAK_ * v) * msk[ch];
    acc += v * w4[k];
  }
  red[t] = acc;
  __syncthreads();
  if (t < 128) red[t] += red[t + 128];
  __syncthreads();
  if (t < 64) {
    float v = red[t] + red[t + 64];
#pragma unroll
    for (int off = 32; off > 0; off >>= 1) v += __shfl_down(v, off);
    if (t == 0) {
      float any = (msk[0] + msk[1] + msk[2] + msk[3] + msk[4] + msk[5] + msk[6] + msk[7]) > 0.f ? 1.f : 0.f;
      out[g] = any / (1.0f + expf(-v));
    }
  }
}

extern "C" void kernel_launch(void* const* d_in, const int* in_sizes, int n_in,
                              void* d_out, int out_size, void* d_ws, size_t ws_size,
                              hipStream_t stream) {
  (void)in_sizes; (void)n_in; (void)out_size; (void)ws_size;
  const float* feat = (const float*)d_in[0];
  const int*   crd  = (const int*)d_in[1];
  const float* w1 = (const float*)d_in[2];
  const float* g1 = (const float*)d_in[3];
  const float* b1 = (const float*)d_in[4];
  const float* w2 = (const float*)d_in[5];
  const float* g2 = (const float*)d_in[6];
  const float* b2 = (const float*)d_in[7];
  const float* w3 = (const float*)d_in[8];
  const float* g3 = (const float*)d_in[9];
  const float* b3 = (const float*)d_in[10];
  const float* w4 = (const float*)d_in[11];
  float* out = (float*)d_out;
  float* ws  = (float*)d_ws;

  int*      cnt    = (int*)(ws + OFF_CNT);
  float*    st     = ws + OFF_STATS;
  int*      start  = (int*)(ws + OFF_START);
  int*      sorted = (int*)(ws + OFF_SORTED);
  int*      aklist = (int*)(ws + OFF_AKLIST);
  int*      plist  = (int*)(ws + OFF_PLIST);
  ushort_t* wt1g   = (ushort_t*)(ws + OFF_WT1);
  ushort_t* wt2g   = (ushort_t*)(ws + OFF_WT2);
  ushort_t* wt3g   = (ushort_t*)(ws + OFF_WT3);
  ushort_t* afb    = (ushort_t*)(ws + OFF_AFEATB);
  ushort_t* x1b    = (ushort_t*)(ws + OFF_X1B);
  int*      cursor = (int*)(ws + OFF_X1B);   // overlays x1b head; dead after k_scatter,
                                             // fully overwritten by conv1m's dense store
  ushort_t* x2b    = (ushort_t*)(ws + OFF_X2B);
  ushort_t* x3b    = (ushort_t*)(ws + OFF_X3B);
  float*    m1     = ws + OFF_M1;
  float*    m2     = ws + OFF_M2;
  float*    m3     = ws + OFF_M3;
  ull_t*    pkctr  = (ull_t*)(st + 644);
  int*      nactk  = (int*)(st + 644);
  int*      nactp  = (int*)(st + 645);

  hipMemsetAsync(d_ws, 0, (size_t)(OFF_STATS + 1024) * sizeof(float), stream);

  k_count<<<(PNUM + 255) / 256, 256, 0, stream>>>(crd, cnt);
  k_alloc<<<NVOX / 4096, 1024, 0, stream>>>(cnt, start, cursor, (int*)(st + 643));
  k_scatter<<<(PNUM + 255) / 256, 256, 0, stream>>>(crd, cursor, sorted);
  k_plist<<<N1S / 1024, 1024, 0, stream>>>(cnt, m1, plist, aklist, pkctr);
  k_avg<<<(PNUM * 8) / 256 + 1, 256, 0, stream>>>(feat, sorted, cnt, start, aklist,
                                                  nactk, afb);
  k_prepw<<<(16384 + 65536 + 131072) / 256, 256, 0, stream>>>(w1, w2, w3, wt1g, wt2g, wt3g);
  k_conv1m<<<N1S / 128, 256, 0, stream>>>(afb, cnt, start, wt1g, x1b, st + 0, st + 64);
  k_convm<64, 64, true, D2,H2,W2, D1,H1,W1><<<N2S / 64, 256, 0, stream>>>(
      x1b, m1, wt2g, g1, b1, st + 0, st + 64, (const void*)nactp,
      x2b, st + 128, st + 256, m2, st + 641);
  k_convm<128, 96, false, D3,H3,W3, D2,H2,W2><<<N3S / 64, 256, 0, stream>>>(
      x2b, m2, wt3g, g2, b2, st + 128, st + 256, (const void*)(st + 641),
      x3b, st + 384, st + 512, m3, st + 642);
  k_final<<<N4S, 256, 0, stream>>>(x3b, m3, w4, g3, b3, st + 384, st + 512, st + 642, out);
}

// Round 10
// 255.802 us; speedup vs baseline: 1.2604x; 1.2347x over previous
//
#include <hip/hip_runtime.h>
#include <math.h>

#define PNUM 300000
#define B_ 2
#define D0 144
#define H0 64
#define W0 160
#define NVOX (B_*D0*H0*W0)   // 2,949,120

#define D1 72
#define H1 32
#define W1 80
#define N1S (B_*D1*H1*W1)   // 368640

#define D2 36
#define H2 16
#define W2 40
#define N2S (B_*D2*H2*W2)   // 46080

#define D3 18
#define H3 8
#define W3 20
#define N3S (B_*D3*H3*W3)   // 5760

#define D4 9
#define H4 4
#define W4 10
#define N4S (B_*D4*H4*W4)   // 720

#define EPS_ 1e-4f
#define LEAK_ 0.2f

typedef __attribute__((ext_vector_type(8))) short v8s;
typedef __attribute__((ext_vector_type(4))) float v4f;

typedef unsigned short ushort_t;
typedef unsigned int uint_t;
typedef unsigned long long ull_t;

__device__ __forceinline__ ushort_t f2b(float f) {
  union { float f; uint_t u; } x; x.f = f;
  uint_t r = x.u + 0x7FFFu + ((x.u >> 16) & 1u);
  return (ushort_t)(r >> 16);
}
__device__ __forceinline__ float b2f(ushort_t h) {
  union { uint_t u; float f; } x; x.u = ((uint_t)h) << 16; return x.f;
}
__device__ __forceinline__ uint_t bn2(uint_t w, float s0, float h0, float s1, float h1,
                                      float msk) {
  float v0 = b2f((ushort_t)(w & 0xffff));
  float v1 = b2f((ushort_t)(w >> 16));
  v0 = fmaf(v0, s0, h0); v1 = fmaf(v1, s1, h1);
  v0 = fmaxf(v0, LEAK_ * v0) * msk;
  v1 = fmaxf(v1, LEAK_ * v1) * msk;
  return (uint_t)f2b(v0) | ((uint_t)f2b(v1) << 16);
}

// workspace layout (4-byte word offsets) -- ~108 MB
#define OFF_CNT     0
#define OFF_STATS   2949120    // 16384 words, see ST_* sub-offsets
#define OFF_START   2965504
#define OFF_SORTED  5914624
#define OFF_AKLIST  6214624
#define OFF_WT1     6514624
#define OFF_WT2     6522816
#define OFF_WT3     6555584
#define OFF_AFEATB  6621120
#define OFF_X1B     11421120
#define OFF_X2B     23217600
#define OFF_X3B     26166720
#define OFF_M1      26535360
#define OFF_M2      26904000
#define OFF_M3      26950080

// stats sub-offsets (within st): partial-sum rows spread same-address atomics
#define ST_S1P  0        // [32][80]
#define ST_Q1P  2560
#define ST_S2P  5120     // [16][144]
#define ST_Q2P  7424
#define ST_S3P  9728     // [16][144]
#define ST_Q3P  12032
#define ST_N2P  14336    // [32]
#define ST_N3P  14368    // [32]
#define ST_GCUR 14400
#define ST_PK   14404    // ull (lo=nactk, hi=nactp)

__device__ __forceinline__ int voxkey(int b, int x, int y, int z) {
  int p = ((b*D1 + (x >> 1))*H1 + (y >> 1))*W1 + (z >> 1);
  int oct = ((x & 1) << 2) | ((y & 1) << 1) | (z & 1);
  return p*8 + oct;
}

// ---------------- densify count ----------------
__global__ __launch_bounds__(256) void k_count(const int* __restrict__ coords,
                                               int* __restrict__ cnt) {
  int i = blockIdx.x * 256 + threadIdx.x;
  if (i >= PNUM) return;
  int4 c = *(const int4*)(coords + i*4);
  atomicAdd(&cnt[voxkey(c.x, c.y, c.z, c.w)], 1);
}

// ---------------- slot allocation: 16384 voxels/block -> 180 ticket atomics ----------------
__global__ __launch_bounds__(1024) void k_alloc(const int* __restrict__ cnt,
                                                int* __restrict__ start,
                                                int* __restrict__ cursor,
                                                int* __restrict__ gcur) {
  __shared__ int wsum[16];
  __shared__ int blockBase;
  int t = threadIdx.x;
  int idx0 = blockIdx.x * 16384 + t * 16;
  int c[16];
  int tsum = 0;
#pragma unroll
  for (int j = 0; j < 4; j++) {
    int4 cv = *(const int4*)(cnt + idx0 + j*4);
    c[j*4+0] = cv.x; c[j*4+1] = cv.y; c[j*4+2] = cv.z; c[j*4+3] = cv.w;
    tsum += cv.x + cv.y + cv.z + cv.w;
  }
  int lane = t & 63, wid = t >> 6;
  int incl = tsum;
#pragma unroll
  for (int off = 1; off < 64; off <<= 1) {
    int v = __shfl_up(incl, off);
    if (lane >= off) incl += v;
  }
  if (lane == 63) wsum[wid] = incl;
  __syncthreads();
  if (t == 0) {
    int tot = 0;
#pragma unroll
    for (int w = 0; w < 16; w++) { int v = wsum[w]; wsum[w] = tot; tot += v; }
    blockBase = atomicAdd(gcur, tot);
  }
  __syncthreads();
  int st = blockBase + wsum[wid] + incl - tsum;
#pragma unroll
  for (int j = 0; j < 4; j++) {
    int4 sv;
    sv.x = st; st += c[j*4+0];
    sv.y = st; st += c[j*4+1];
    sv.z = st; st += c[j*4+2];
    sv.w = st; st += c[j*4+3];
    *(int4*)(start + idx0 + j*4) = sv;
    *(int4*)(cursor + idx0 + j*4) = sv;
  }
}

// ---------------- counting-sort scatter ----------------
__global__ __launch_bounds__(256) void k_scatter(const int* __restrict__ coords,
                                                 int* __restrict__ cursor,
                                                 int* __restrict__ sorted) {
  int i = blockIdx.x * 256 + threadIdx.x;
  if (i >= PNUM) return;
  int4 c = *(const int4*)(coords + i*4);
  int slot = atomicAdd(&cursor[voxkey(c.x, c.y, c.z, c.w)], 1);
  sorted[slot] = i;
}

// ---------------- compaction: 4 parents/thread -> 90 ticket atomics ----------------
__global__ __launch_bounds__(1024) void k_plist(const int* __restrict__ cnt,
                                                float* __restrict__ m1,
                                                int* __restrict__ aklist,
                                                ull_t* __restrict__ pkctr) {
  __shared__ int wsum[16];
  __shared__ ull_t sbase;
  int t = threadIdx.x;
  int p0 = blockIdx.x * 4096 + t * 4;
  int lane = t & 63, wid = t >> 6;
  uint_t mb[4];
  int packed = 0;
#pragma unroll
  for (int j = 0; j < 4; j++) {
    const int4* c4 = (const int4*)(cnt + (size_t)(p0 + j)*8);
    int4 a = c4[0], b = c4[1];
    uint_t m = 0;
    m |= (a.x > 0) ? 1u : 0; m |= (a.y > 0) ? 2u : 0;
    m |= (a.z > 0) ? 4u : 0; m |= (a.w > 0) ? 8u : 0;
    m |= (b.x > 0) ? 16u : 0; m |= (b.y > 0) ? 32u : 0;
    m |= (b.z > 0) ? 64u : 0; m |= (b.w > 0) ? 128u : 0;
    mb[j] = m;
    int ck = __popc(m);
    int pa = (ck > 0) ? 1 : 0;
    m1[p0 + j] = pa ? 1.f : 0.f;
    packed += (pa << 16) | ck;
  }
  int incl = packed;
#pragma unroll
  for (int o = 1; o < 64; o <<= 1) {
    int v = __shfl_up(incl, o);
    if (lane >= o) incl += v;
  }
  if (lane == 63) wsum[wid] = incl;
  __syncthreads();
  if (t == 0) {
    int tot = 0;
#pragma unroll
    for (int w = 0; w < 16; w++) { int v = wsum[w]; wsum[w] = tot; tot += v; }
    ull_t add = ((ull_t)(uint_t)(tot >> 16) << 32) | (ull_t)(uint_t)(tot & 0xffff);
    sbase = atomicAdd(pkctr, add);
  }
  __syncthreads();
  ull_t base = sbase;
  int excl = wsum[wid] + incl - packed;
  int koff = (int)(base & 0xffffffffULL) + (excl & 0xffff);
#pragma unroll
  for (int j = 0; j < 4; j++) {
    uint_t m = mb[j];
    while (m) {
      int i = __ffs(m) - 1; m &= m - 1;
      aklist[koff++] = (p0 + j)*8 + i;
    }
  }
}

// ---------------- duplicate-averaging -> bf16 afeat (8 threads/key) ----------------
__global__ __launch_bounds__(256) void k_avg(const float* __restrict__ feat,
                                             const int* __restrict__ sorted,
                                             const int* __restrict__ cnt,
                                             const int* __restrict__ start,
                                             const int* __restrict__ aklist,
                                             const int* __restrict__ nactk,
                                             ushort_t* __restrict__ afb) {
  int gid = blockIdx.x * 256 + threadIdx.x;
  int j = gid >> 3;
  if (j >= nactk[0]) return;
  int key = aklist[j];
  int c = cnt[key];
  int s0 = start[key];
  int q = (gid & 7) * 4;
  float4 acc = {0.f, 0.f, 0.f, 0.f};
  for (int i = 0; i < c; i++) {
    float4 v = *(const float4*)(feat + (size_t)sorted[s0 + i] * 32 + q);
    acc.x += v.x; acc.y += v.y; acc.z += v.z; acc.w += v.w;
  }
  float inv = 1.f / (float)c;
  uint2 o;
  o.x = (uint_t)f2b(acc.x*inv) | ((uint_t)f2b(acc.y*inv) << 16);
  o.y = (uint_t)f2b(acc.z*inv) | ((uint_t)f2b(acc.w*inv) << 16);
  *(uint2*)(afb + (size_t)s0 * 32 + q) = o;
}

// ---------------- weight prep: bf16 + [chunk32][cout][32] layout ----------------
__global__ __launch_bounds__(256) void k_prepw(const float* __restrict__ w1,
                                               const float* __restrict__ w2,
                                               const float* __restrict__ w3,
                                               ushort_t* __restrict__ wt1,
                                               ushort_t* __restrict__ wt2,
                                               ushort_t* __restrict__ wt3) {
  int idx = blockIdx.x * 256 + threadIdx.x;
  if (idx < 16384) {
    int c = idx >> 11, r = idx & 2047;
    int co = r >> 5, kk = r & 31;
    wt1[idx] = f2b(w1[(c*32 + kk)*64 + co]);
  } else if (idx < 16384 + 65536) {
    int i = idx - 16384;
    int c = i >> 12, r = i & 4095;
    int co = r >> 5, kk = r & 31;
    int k = c*32 + kk;
    wt2[i] = (co < 96) ? f2b(w2[k*96 + co]) : 0;
  } else if (idx < 16384 + 65536 + 131072) {
    int i = idx - 81920;
    int c = i >> 12, r = i & 4095;
    int co = r >> 5, kk = r & 31;
    int k = c*32 + kk;
    int ch = k >> 7, ci = k & 127;
    wt3[i] = (ci < 96) ? f2b(w3[(ch*96 + ci)*128 + co]) : 0;
  }
}

// ---------------- MFMA conv1: stats into 32-way-spread partial rows ----------------
__global__ __launch_bounds__(256) void k_conv1m(
    const ushort_t* __restrict__ afb, const int* __restrict__ cnt,
    const int* __restrict__ start, const ushort_t* __restrict__ wtg,
    ushort_t* __restrict__ x1b, float* __restrict__ sp, float* __restrict__ qp) {
  __shared__ __align__(16) ushort_t wlds[16384];
  __shared__ int cst[128*9];
  __shared__ float redS[4][64], redQ[4][64];
  int t = threadIdx.x;
#pragma unroll
  for (int i = 0; i < 8; i++)
    ((uint4*)wlds)[t + i*256] = ((const uint4*)wtg)[t + i*256];
  if (t < 128) {
    int p = blockIdx.x * 128 + t;
    const int4* cp = (const int4*)(cnt + (size_t)p*8);
    const int4* spt = (const int4*)(start + (size_t)p*8);
    int4 c0 = cp[0], c1 = cp[1], s0 = spt[0], s1 = spt[1];
    cst[t*9 + 0] = (c0.x > 0) ? s0.x : -1;
    cst[t*9 + 1] = (c0.y > 0) ? s0.y : -1;
    cst[t*9 + 2] = (c0.z > 0) ? s0.z : -1;
    cst[t*9 + 3] = (c0.w > 0) ? s0.w : -1;
    cst[t*9 + 4] = (c1.x > 0) ? s1.x : -1;
    cst[t*9 + 5] = (c1.y > 0) ? s1.y : -1;
    cst[t*9 + 6] = (c1.z > 0) ? s1.z : -1;
    cst[t*9 + 7] = (c1.w > 0) ? s1.w : -1;
  }
  __syncthreads();
  int lane = t & 63, wv = t >> 6;
  int l15 = lane & 15, q = lane >> 4;
  int SB = wv * 32;
  v8s a[8][2];
#pragma unroll
  for (int c = 0; c < 8; c++) {
#pragma unroll
    for (int mt = 0; mt < 2; mt++) {
      int site = SB + mt*16 + l15;
      int sp2 = cst[site*9 + c];
      v8s av = {0,0,0,0,0,0,0,0};
      if (sp2 >= 0) av = *(const v8s*)(afb + (size_t)sp2*32 + q*8);
      a[c][mt] = av;
    }
  }
  v4f acc[2][4];
#pragma unroll
  for (int i = 0; i < 2; i++)
#pragma unroll
    for (int j = 0; j < 4; j++) acc[i][j] = (v4f){0.f, 0.f, 0.f, 0.f};
#pragma unroll
  for (int c = 0; c < 8; c++) {
    v8s b[4];
#pragma unroll
    for (int nt = 0; nt < 4; nt++)
      b[nt] = *(const v8s*)&wlds[c*2048 + (nt*16 + l15)*32 + q*8];
#pragma unroll
    for (int mt = 0; mt < 2; mt++)
#pragma unroll
      for (int nt = 0; nt < 4; nt++)
        acc[mt][nt] = __builtin_amdgcn_mfma_f32_16x16x32_bf16(a[c][mt], b[nt], acc[mt][nt], 0, 0, 0);
  }
  int pbase = blockIdx.x * 128;
  float ss[4] = {0,0,0,0}, sq[4] = {0,0,0,0};
#pragma unroll
  for (int mt = 0; mt < 2; mt++) {
#pragma unroll
    for (int nt = 0; nt < 4; nt++) {
#pragma unroll
      for (int r = 0; r < 4; r++) {
        int sl = SB + mt*16 + q*4 + r;
        ushort_t h = f2b(acc[mt][nt][r]);
        float v = b2f(h);
        x1b[(size_t)(pbase + sl)*64 + nt*16 + l15] = h;
        ss[nt] += v; sq[nt] += v*v;
      }
    }
  }
#pragma unroll
  for (int nt = 0; nt < 4; nt++) {
    float v1 = ss[nt], v2 = sq[nt];
    v1 += __shfl_xor(v1, 16); v1 += __shfl_xor(v1, 32);
    v2 += __shfl_xor(v2, 16); v2 += __shfl_xor(v2, 32);
    if (lane < 16) { redS[wv][nt*16 + l15] = v1; redQ[wv][nt*16 + l15] = v2; }
  }
  __syncthreads();
  if (t < 64) {
    float s = redS[0][t] + redS[1][t] + redS[2][t] + redS[3][t];
    float qq = redQ[0][t] + redQ[1][t] + redQ[2][t] + redQ[3][t];
    int row = (blockIdx.x & 31) * 80;
    atomicAdd(&sp[row + t], s);
    atomicAdd(&qp[row + t], qq);
  }
}

// ---------------- MFMA conv (conv2/conv3) ----------------
// prologue reduces NROW partial-stat rows; epilogue writes 16-way-spread partials.
template <int CSTRIDE, int CIN_REAL, bool NINT, int NROW, int INSTR,
          int DO, int HO, int WO, int DP, int HP, int WP>
__global__ __launch_bounds__(256) void k_convm(
    const ushort_t* __restrict__ xin, const float* __restrict__ mprev,
    const ushort_t* __restrict__ wtg,
    const float* __restrict__ gam, const float* __restrict__ bet,
    const float* __restrict__ spin, const float* __restrict__ qpin,
    const void* __restrict__ ncnt, const float* __restrict__ npin,
    ushort_t* __restrict__ xout, float* __restrict__ osum, float* __restrict__ osq,
    float* __restrict__ mout, float* __restrict__ npart) {
  const int NCHUNK = CSTRIDE / 4;
  __shared__ __align__(16) float sc[CSTRIDE], sh[CSTRIDE];
  __shared__ int   cbase[64*9];
  __shared__ float cmask[64*9];
  __shared__ float redS[4][64], redQ[4][64];
  int t = threadIdx.x;
  if (t < CSTRIDE) {
    float scv = 0.f, shv = 0.f;
    if (t < CIN_REAL) {
      float n;
      if (NINT) n = fmaxf((float)((const int*)ncnt)[0], 1.0f);
      else {
        float nn = 0.f;
        for (int r = 0; r < 32; r++) nn += npin[r];
        n = fmaxf(nn, 1.0f);
      }
      float s1 = 0.f, q1 = 0.f;
      for (int r = 0; r < NROW; r++) { s1 += spin[r*INSTR + t]; q1 += qpin[r*INSTR + t]; }
      float mean = s1 / n;
      float var = q1 / n - mean * mean;
      float s = gam[t] * rsqrtf(var + EPS_);
      scv = s; shv = bet[t] - mean * s;
    }
    sc[t] = scv; sh[t] = shv;
  }
#pragma unroll
  for (int ii = 0; ii < 2; ii++) {
    int idx = t + ii*256;
    int s = idx >> 3, ch = idx & 7;
    int g = blockIdx.x * 64 + s;
    int b = g / (DO*HO*WO); int r = g - b*(DO*HO*WO);
    int ox = r / (HO*WO); r -= ox*(HO*WO);
    int oy = r / WO; int oz = r - oy*WO;
    int ps = ((b*DP + 2*ox + ((ch >> 2) & 1))*HP + 2*oy + ((ch >> 1) & 1))*WP + 2*oz + (ch & 1);
    cbase[s*9 + ch] = ps * CSTRIDE;
    cmask[s*9 + ch] = mprev[ps];
  }
  __syncthreads();
  int lane = t & 63, wv = t >> 6;
  int l15 = lane & 15, q = lane >> 4;
  int SB = (wv & 1) * 32, NB = (wv >> 1) * 64;
  v4f acc[2][4];
#pragma unroll
  for (int i = 0; i < 2; i++)
#pragma unroll
    for (int j = 0; j < 4; j++) acc[i][j] = (v4f){0.f, 0.f, 0.f, 0.f};
  uint4 rawN[2]; float mskN[2]; v8s bN[4];
#pragma unroll
  for (int mt = 0; mt < 2; mt++) {
    int site = SB + mt*16 + l15;
    rawN[mt] = *(const uint4*)(xin + (size_t)cbase[site*9] + q*8);
    mskN[mt] = cmask[site*9];
  }
#pragma unroll
  for (int nt = 0; nt < 4; nt++)
    bN[nt] = *(const v8s*)(wtg + (NB + nt*16 + l15)*32 + q*8);
#pragma unroll
  for (int c = 0; c < NCHUNK; c++) {
    uint4 raw[2] = {rawN[0], rawN[1]};
    float mskc[2] = {mskN[0], mskN[1]};
    v8s b[4] = {bN[0], bN[1], bN[2], bN[3]};
    if (c + 1 < NCHUNK) {
      int ch1 = ((c+1) * 32) / CSTRIDE;
      int cio1 = ((c+1) * 32) % CSTRIDE + q * 8;
#pragma unroll
      for (int mt = 0; mt < 2; mt++) {
        int site = SB + mt*16 + l15;
        rawN[mt] = *(const uint4*)(xin + (size_t)cbase[site*9 + ch1] + cio1);
        mskN[mt] = cmask[site*9 + ch1];
      }
#pragma unroll
      for (int nt = 0; nt < 4; nt++)
        bN[nt] = *(const v8s*)(wtg + (size_t)(c+1)*4096 + (NB + nt*16 + l15)*32 + q*8);
    }
    int cio = (c * 32) % CSTRIDE + q * 8;
    float4 sc0 = *(const float4*)&sc[cio];
    float4 sc1 = *(const float4*)&sc[cio + 4];
    float4 sh0 = *(const float4*)&sh[cio];
    float4 sh1 = *(const float4*)&sh[cio + 4];
    v8s a[2];
#pragma unroll
    for (int mt = 0; mt < 2; mt++) {
      int4 pk;
      pk.x = (int)bn2(raw[mt].x, sc0.x, sh0.x, sc0.y, sh0.y, mskc[mt]);
      pk.y = (int)bn2(raw[mt].y, sc0.z, sh0.z, sc0.w, sh0.w, mskc[mt]);
      pk.z = (int)bn2(raw[mt].z, sc1.x, sh1.x, sc1.y, sh1.y, mskc[mt]);
      pk.w = (int)bn2(raw[mt].w, sc1.z, sh1.z, sc1.w, sh1.w, mskc[mt]);
      a[mt] = *(v8s*)&pk;
    }
#pragma unroll
    for (int mt = 0; mt < 2; mt++)
#pragma unroll
      for (int nt = 0; nt < 4; nt++)
        acc[mt][nt] = __builtin_amdgcn_mfma_f32_16x16x32_bf16(a[mt], b[nt], acc[mt][nt], 0, 0, 0);
  }
  float ss[4] = {0,0,0,0}, sq[4] = {0,0,0,0};
#pragma unroll
  for (int mt = 0; mt < 2; mt++) {
#pragma unroll
    for (int nt = 0; nt < 4; nt++) {
#pragma unroll
      for (int r = 0; r < 4; r++) {
        int sl = SB + mt*16 + q*4 + r;
        size_t gsite = (size_t)blockIdx.x * 64 + sl;
        ushort_t h = f2b(acc[mt][nt][r]);
        float v = b2f(h);
        xout[gsite*128 + NB + nt*16 + l15] = h;
        ss[nt] += v; sq[nt] += v*v;
      }
    }
  }
  if (t < 64) {
    bool act = false;
#pragma unroll
    for (int ch = 0; ch < 8; ch++) act |= (cmask[t*9 + ch] > 0.f);
    mout[blockIdx.x * 64 + t] = act ? 1.f : 0.f;
    unsigned long long bal = __ballot(act);
    if (t == 0) atomicAdd(&npart[blockIdx.x & 31], (float)__popcll(bal));
  }
#pragma unroll
  for (int nt = 0; nt < 4; nt++) {
    float v1 = ss[nt], v2 = sq[nt];
    v1 += __shfl_xor(v1, 16); v1 += __shfl_xor(v1, 32);
    v2 += __shfl_xor(v2, 16); v2 += __shfl_xor(v2, 32);
    if (lane < 16) { redS[wv][nt*16 + l15] = v1; redQ[wv][nt*16 + l15] = v2; }
  }
  __syncthreads();
  if (t < 128) {
    float s, qq;
    if (t < 64) { s = redS[0][t] + redS[1][t]; qq = redQ[0][t] + redQ[1][t]; }
    else        { s = redS[2][t-64] + redS[3][t-64]; qq = redQ[2][t-64] + redQ[3][t-64]; }
    int row = (blockIdx.x & 15) * 144;
    atomicAdd(&osum[row + t], s);
    atomicAdd(&osq[row + t], qq);
  }
}

// ---------------- final conv (cout=1) + sigmoid + mask ----------------
__global__ __launch_bounds__(256) void k_final(
    const ushort_t* __restrict__ x3b, const float* __restrict__ m3,
    const float* __restrict__ w4, const float* __restrict__ gam,
    const float* __restrict__ bet, const float* __restrict__ spin,
    const float* __restrict__ qpin, const float* __restrict__ npin,
    float* __restrict__ out) {
  __shared__ float sc[128], sh[128];
  __shared__ int cb[8];
  __shared__ float msk[8];
  __shared__ float red[256];
  int t = threadIdx.x;
  if (t < 128) {
    float nn = 0.f;
    for (int r = 0; r < 32; r++) nn += npin[r];
    float n = fmaxf(nn, 1.0f);
    float s1 = 0.f, q1 = 0.f;
    for (int r = 0; r < 16; r++) { s1 += spin[r*144 + t]; q1 += qpin[r*144 + t]; }
    float mean = s1 / n;
    float var = q1 / n - mean * mean;
    float s = gam[t] * rsqrtf(var + EPS_);
    sc[t] = s; sh[t] = bet[t] - mean * s;
  }
  int g = blockIdx.x;
  int b = g / (D4*H4*W4); int r = g - b*(D4*H4*W4);
  int ox = r / (H4*W4); r -= ox*(H4*W4);
  int oy = r / W4; int oz = r - oy*W4;
  if (t < 8) {
    int ps = ((b*D3 + 2*ox + ((t >> 2) & 1))*H3 + 2*oy + ((t >> 1) & 1))*W3 + 2*oz + (t & 1);
    cb[t] = ps * 128;
    msk[t] = m3[ps];
  }
  __syncthreads();
  float acc = 0.f;
#pragma unroll
  for (int ii = 0; ii < 4; ii++) {
    int k = t + ii*256;
    int ch = k >> 7, ci = k & 127;
    float v = b2f(x3b[cb[ch] + ci]);
    v = v * sc[ci] + sh[ci];
    v = (v > 0.f ? v : LEAK_ * v) * msk[ch];
    acc += v * w4[k];
  }
  red[t] = acc;
  __syncthreads();
  if (t < 128) red[t] += red[t + 128];
  __syncthreads();
  if (t < 64) {
    float v = red[t] + red[t + 64];
#pragma unroll
    for (int off = 32; off > 0; off >>= 1) v += __shfl_down(v, off);
    if (t == 0) {
      float any = (msk[0] + msk[1] + msk[2] + msk[3] + msk[4] + msk[5] + msk[6] + msk[7]) > 0.f ? 1.f : 0.f;
      out[g] = any / (1.0f + expf(-v));
    }
  }
}

extern "C" void kernel_launch(void* const* d_in, const int* in_sizes, int n_in,
                              void* d_out, int out_size, void* d_ws, size_t ws_size,
                              hipStream_t stream) {
  (void)in_sizes; (void)n_in; (void)out_size; (void)ws_size;
  const float* feat = (const float*)d_in[0];
  const int*   crd  = (const int*)d_in[1];
  const float* w1 = (const float*)d_in[2];
  const float* g1 = (const float*)d_in[3];
  const float* b1 = (const float*)d_in[4];
  const float* w2 = (const float*)d_in[5];
  const float* g2 = (const float*)d_in[6];
  const float* b2 = (const float*)d_in[7];
  const float* w3 = (const float*)d_in[8];
  const float* g3 = (const float*)d_in[9];
  const float* b3 = (const float*)d_in[10];
  const float* w4 = (const float*)d_in[11];
  float* out = (float*)d_out;
  float* ws  = (float*)d_ws;

  int*      cnt    = (int*)(ws + OFF_CNT);
  float*    st     = ws + OFF_STATS;
  int*      start  = (int*)(ws + OFF_START);
  int*      sorted = (int*)(ws + OFF_SORTED);
  int*      aklist = (int*)(ws + OFF_AKLIST);
  ushort_t* wt1g   = (ushort_t*)(ws + OFF_WT1);
  ushort_t* wt2g   = (ushort_t*)(ws + OFF_WT2);
  ushort_t* wt3g   = (ushort_t*)(ws + OFF_WT3);
  ushort_t* afb    = (ushort_t*)(ws + OFF_AFEATB);
  ushort_t* x1b    = (ushort_t*)(ws + OFF_X1B);
  int*      cursor = (int*)(ws + OFF_X1B);   // overlay; dead after k_scatter
  ushort_t* x2b    = (ushort_t*)(ws + OFF_X2B);
  ushort_t* x3b    = (ushort_t*)(ws + OFF_X3B);
  float*    m1     = ws + OFF_M1;
  float*    m2     = ws + OFF_M2;
  float*    m3     = ws + OFF_M3;
  ull_t*    pkctr  = (ull_t*)(st + ST_PK);
  int*      nactk  = (int*)(st + ST_PK);
  int*      nactp  = (int*)(st + ST_PK + 1);

  hipMemsetAsync(d_ws, 0, (size_t)(OFF_STATS + 16384) * sizeof(float), stream);

  k_count<<<(PNUM + 255) / 256, 256, 0, stream>>>(crd, cnt);
  k_alloc<<<NVOX / 16384, 1024, 0, stream>>>(cnt, start, cursor, (int*)(st + ST_GCUR));
  k_scatter<<<(PNUM + 255) / 256, 256, 0, stream>>>(crd, cursor, sorted);
  k_plist<<<N1S / 4096, 1024, 0, stream>>>(cnt, m1, aklist, pkctr);
  k_avg<<<(PNUM * 8) / 256 + 1, 256, 0, stream>>>(feat, sorted, cnt, start, aklist,
                                                  nactk, afb);
  k_prepw<<<(16384 + 65536 + 131072) / 256, 256, 0, stream>>>(w1, w2, w3, wt1g, wt2g, wt3g);
  k_conv1m<<<N1S / 128, 256, 0, stream>>>(afb, cnt, start, wt1g, x1b,
                                          st + ST_S1P, st + ST_Q1P);
  k_convm<64, 64, true, 32, 80, D2,H2,W2, D1,H1,W1><<<N2S / 64, 256, 0, stream>>>(
      x1b, m1, wt2g, g1, b1, st + ST_S1P, st + ST_Q1P, (const void*)nactp, nullptr,
      x2b, st + ST_S2P, st + ST_Q2P, m2, st + ST_N2P);
  k_convm<128, 96, false, 16, 144, D3,H3,W3, D2,H2,W2><<<N3S / 64, 256, 0, stream>>>(
      x2b, m2, wt3g, g2, b2, st + ST_S2P, st + ST_Q2P, nullptr, st + ST_N2P,
      x3b, st + ST_S3P, st + ST_Q3P, m3, st + ST_N3P);
  k_final<<<N4S, 256, 0, stream>>>(x3b, m3, w4, g3, b3,
                                   st + ST_S3P, st + ST_Q3P, st + ST_N3P, out);
}

// Round 11
// 245.717 us; speedup vs baseline: 1.3121x; 1.0410x over previous
//
#include <hip/hip_runtime.h>
#include <math.h>

#define PNUM 300000
#define B_ 2
#define D0 144
#define H0 64
#define W0 160
#define NVOX (B_*D0*H0*W0)   // 2,949,120

#define D1 72
#define H1 32
#define W1 80
#define N1S (B_*D1*H1*W1)   // 368640

#define D2 36
#define H2 16
#define W2 40
#define N2S (B_*D2*H2*W2)   // 46080

#define D3 18
#define H3 8
#define W3 20
#define N3S (B_*D3*H3*W3)   // 5760

#define D4 9
#define H4 4
#define W4 10
#define N4S (B_*D4*H4*W4)   // 720

#define EPS_ 1e-4f
#define LEAK_ 0.2f

typedef __attribute__((ext_vector_type(8))) short v8s;
typedef __attribute__((ext_vector_type(4))) float v4f;

typedef unsigned short ushort_t;
typedef unsigned int uint_t;
typedef unsigned long long ull_t;

__device__ __forceinline__ ushort_t f2b(float f) {
  union { float f; uint_t u; } x; x.f = f;
  uint_t r = x.u + 0x7FFFu + ((x.u >> 16) & 1u);
  return (ushort_t)(r >> 16);
}
__device__ __forceinline__ float b2f(ushort_t h) {
  union { uint_t u; float f; } x; x.u = ((uint_t)h) << 16; return x.f;
}
__device__ __forceinline__ uint_t bn2(uint_t w, float s0, float h0, float s1, float h1,
                                      float msk) {
  float v0 = b2f((ushort_t)(w & 0xffff));
  float v1 = b2f((ushort_t)(w >> 16));
  v0 = fmaf(v0, s0, h0); v1 = fmaf(v1, s1, h1);
  v0 = fmaxf(v0, LEAK_ * v0) * msk;
  v1 = fmaxf(v1, LEAK_ * v1) * msk;
  return (uint_t)f2b(v0) | ((uint_t)f2b(v1) << 16);
}

// map a linear site index in grid (DD,HH,WW) to next-level-grouped key:
// parent_linear*8 + octant. Bijection; makes the CONSUMER's 8-child gather contiguous.
template <int DD, int HH, int WW>
__device__ __forceinline__ int okey(int p) {
  int b = p / (DD*HH*WW); int r = p - b*(DD*HH*WW);
  int x = r / (HH*WW); r -= x*(HH*WW);
  int y = r / WW; int z = r - y*WW;
  return (((((b*(DD/2) + (x >> 1))*(HH/2) + (y >> 1))*(WW/2)) + (z >> 1)) << 3)
         | ((x & 1) << 2) | ((y & 1) << 1) | (z & 1);
}

// workspace layout (4-byte word offsets) -- ~108 MB
#define OFF_CNT     0          // NVOX ints (key = L1parent*8+octant)
#define OFF_STATS   2949120    // 16384 words
#define OFF_CURSOR  2965504    // NVOX ints (after scatter: cursor = start + cnt)
#define OFF_SORTED  5914624
#define OFF_AKLIST  6214624
#define OFF_WT1     6514624
#define OFF_WT2     6522816
#define OFF_WT3     6555584
#define OFF_AFEATB  6621120
#define OFF_X1B     11421120   // bf16, okey1-grouped
#define OFF_X2B     23217600   // bf16, okey2-grouped
#define OFF_X3B     26166720   // bf16, okey3-grouped
#define OFF_M1      26535360   // okey1-grouped
#define OFF_M2      26904000   // okey2-grouped
#define OFF_M3      26950080   // okey3-grouped

#define ST_S1P  0        // [32][80]
#define ST_Q1P  2560
#define ST_S2P  5120     // [16][144]
#define ST_Q2P  7424
#define ST_S3P  9728
#define ST_Q3P  12032
#define ST_N2P  14336    // [32]
#define ST_N3P  14368    // [32]
#define ST_GCUR 14400
#define ST_PK   14404    // ull (lo=nactk, hi=nactp)

__device__ __forceinline__ int voxkey(int b, int x, int y, int z) {
  int p = ((b*D1 + (x >> 1))*H1 + (y >> 1))*W1 + (z >> 1);
  int oct = ((x & 1) << 2) | ((y & 1) << 1) | (z & 1);
  return p*8 + oct;
}

// ---------------- fused front-end: densify count + weight prep + stats zero ----------------
#define NB_COUNT 1172
#define NB_PREPW 832
#define NB_STZ   16
__global__ __launch_bounds__(256) void k_front(
    const int* __restrict__ coords, int* __restrict__ cnt,
    const float* __restrict__ w1, const float* __restrict__ w2,
    const float* __restrict__ w3,
    ushort_t* __restrict__ wt1, ushort_t* __restrict__ wt2,
    ushort_t* __restrict__ wt3, float* __restrict__ stz) {
  int bb = blockIdx.x, t = threadIdx.x;
  if (bb < NB_COUNT) {
    int i = bb * 256 + t;
    if (i < PNUM) {
      int4 c = *(const int4*)(coords + i*4);
      atomicAdd(&cnt[voxkey(c.x, c.y, c.z, c.w)], 1);
    }
  } else if (bb < NB_COUNT + NB_PREPW) {
    int idx = (bb - NB_COUNT) * 256 + t;
    if (idx < 16384) {
      int c = idx >> 11, r = idx & 2047;
      int co = r >> 5, kk = r & 31;
      wt1[idx] = f2b(w1[(c*32 + kk)*64 + co]);
    } else if (idx < 16384 + 65536) {
      int i = idx - 16384;
      int c = i >> 12, r = i & 4095;
      int co = r >> 5, kk = r & 31;
      int k = c*32 + kk;
      wt2[i] = (co < 96) ? f2b(w2[k*96 + co]) : 0;
    } else {
      int i = idx - 81920;
      int c = i >> 12, r = i & 4095;
      int co = r >> 5, kk = r & 31;
      int k = c*32 + kk;
      int ch = k >> 7, ci = k & 127;
      wt3[i] = (ci < 96) ? f2b(w3[(ch*96 + ci)*128 + co]) : 0;
    }
  } else {
    int off = ((bb - NB_COUNT - NB_PREPW) * 256 + t) * 4;
    *(float4*)(stz + off) = make_float4(0.f, 0.f, 0.f, 0.f);
  }
}

// ---------------- fused alloc + compaction: cursor, m1 (okey order), aklist ----------------
// 16384 keys (2048 parents) per block; single 64-bit combined scan (slots hi, pk lo);
// 2 ticket atomics/block on independent addresses.
__global__ __launch_bounds__(1024) void k_alloc(const int* __restrict__ cnt,
                                                int* __restrict__ cursor,
                                                float* __restrict__ m1b,
                                                int* __restrict__ aklist,
                                                int* __restrict__ gcur,
                                                ull_t* __restrict__ pkctr) {
  __shared__ ull_t wsum[16];
  __shared__ int slotBase;
  __shared__ ull_t pkBase;
  int t = threadIdx.x;
  int idx0 = blockIdx.x * 16384 + t * 16;
  int c[16];
  int tsum = 0;
#pragma unroll
  for (int j = 0; j < 4; j++) {
    int4 cv = *(const int4*)(cnt + idx0 + j*4);
    c[j*4+0] = cv.x; c[j*4+1] = cv.y; c[j*4+2] = cv.z; c[j*4+3] = cv.w;
    tsum += cv.x + cv.y + cv.z + cv.w;
  }
  uint_t m0 = 0, m1m = 0;
#pragma unroll
  for (int j = 0; j < 8; j++) { if (c[j] > 0) m0 |= (1u << j); }
#pragma unroll
  for (int j = 0; j < 8; j++) { if (c[8+j] > 0) m1m |= (1u << j); }
  int ck = __popc(m0) + __popc(m1m);
  int pa = ((m0 != 0) ? 1 : 0) + ((m1m != 0) ? 1 : 0);
  ull_t sv = ((ull_t)(uint_t)tsum << 32) | (ull_t)(uint_t)((pa << 16) | ck);
  int lane = t & 63, wid = t >> 6;
  ull_t incl = sv;
#pragma unroll
  for (int o = 1; o < 64; o <<= 1) {
    ull_t v = __shfl_up(incl, o);
    if (lane >= o) incl += v;
  }
  if (lane == 63) wsum[wid] = incl;
  __syncthreads();
  if (t == 0) {
    ull_t tot = 0;
#pragma unroll
    for (int w = 0; w < 16; w++) { ull_t v = wsum[w]; wsum[w] = tot; tot += v; }
    slotBase = atomicAdd(gcur, (int)(tot >> 32));
    uint_t pk = (uint_t)(tot & 0xffffffffULL);
    pkBase = atomicAdd(pkctr, ((ull_t)(pk >> 16) << 32) | (ull_t)(pk & 0xffff));
  }
  __syncthreads();
  ull_t excl = wsum[wid] + incl - sv;
  int st = slotBase + (int)(excl >> 32);
  uint_t pkl = (uint_t)(excl & 0xffffffffULL);
  int koff = (int)(pkBase & 0xffffffffULL) + (int)(pkl & 0xffff);
#pragma unroll
  for (int j = 0; j < 4; j++) {
    int4 sv2;
    sv2.x = st; st += c[j*4+0];
    sv2.y = st; st += c[j*4+1];
    sv2.z = st; st += c[j*4+2];
    sv2.w = st; st += c[j*4+3];
    *(int4*)(cursor + idx0 + j*4) = sv2;
  }
  int p0 = idx0 >> 3;
  m1b[okey<D1,H1,W1>(p0)]     = (m0 != 0) ? 1.f : 0.f;
  m1b[okey<D1,H1,W1>(p0 + 1)] = (m1m != 0) ? 1.f : 0.f;
  uint_t m = m0;
  while (m) { int i = __ffs(m) - 1; m &= m - 1; aklist[koff++] = p0*8 + i; }
  m = m1m;
  while (m) { int i = __ffs(m) - 1; m &= m - 1; aklist[koff++] = (p0 + 1)*8 + i; }
}

// ---------------- counting-sort scatter ----------------
__global__ __launch_bounds__(256) void k_scatter(const int* __restrict__ coords,
                                                 int* __restrict__ cursor,
                                                 int* __restrict__ sorted) {
  int i = blockIdx.x * 256 + threadIdx.x;
  if (i >= PNUM) return;
  int4 c = *(const int4*)(coords + i*4);
  int slot = atomicAdd(&cursor[voxkey(c.x, c.y, c.z, c.w)], 1);
  sorted[slot] = i;
}

// ---------------- duplicate-averaging -> bf16 afeat (start = cursor - cnt) ----------------
__global__ __launch_bounds__(256) void k_avg(const float* __restrict__ feat,
                                             const int* __restrict__ sorted,
                                             const int* __restrict__ cnt,
                                             const int* __restrict__ cursor,
                                             const int* __restrict__ aklist,
                                             const int* __restrict__ nactk,
                                             ushort_t* __restrict__ afb) {
  int gid = blockIdx.x * 256 + threadIdx.x;
  int j = gid >> 3;
  if (j >= nactk[0]) return;
  int key = aklist[j];
  int c = cnt[key];
  int s0 = cursor[key] - c;
  int q = (gid & 7) * 4;
  float4 acc = {0.f, 0.f, 0.f, 0.f};
  for (int i = 0; i < c; i++) {
    float4 v = *(const float4*)(feat + (size_t)sorted[s0 + i] * 32 + q);
    acc.x += v.x; acc.y += v.y; acc.z += v.z; acc.w += v.w;
  }
  float inv = 1.f / (float)c;
  uint2 o;
  o.x = (uint_t)f2b(acc.x*inv) | ((uint_t)f2b(acc.y*inv) << 16);
  o.y = (uint_t)f2b(acc.z*inv) | ((uint_t)f2b(acc.w*inv) << 16);
  *(uint2*)(afb + (size_t)s0 * 32 + q) = o;
}

// ---------------- MFMA conv1: x1b written in okey1 order ----------------
__global__ __launch_bounds__(256) void k_conv1m(
    const ushort_t* __restrict__ afb, const int* __restrict__ cnt,
    const int* __restrict__ cursor, const ushort_t* __restrict__ wtg,
    ushort_t* __restrict__ x1b, float* __restrict__ sp, float* __restrict__ qp) {
  __shared__ __align__(16) ushort_t wlds[16384];
  __shared__ int cst[128*9];
  __shared__ int okl[128];
  __shared__ float redS[4][64], redQ[4][64];
  int t = threadIdx.x;
#pragma unroll
  for (int i = 0; i < 8; i++)
    ((uint4*)wlds)[t + i*256] = ((const uint4*)wtg)[t + i*256];
  if (t < 128) {
    int p = blockIdx.x * 128 + t;
    okl[t] = okey<D1,H1,W1>(p);
    const int4* cp = (const int4*)(cnt + (size_t)p*8);
    const int4* up = (const int4*)(cursor + (size_t)p*8);
    int4 c0 = cp[0], c1 = cp[1], u0 = up[0], u1 = up[1];
    cst[t*9 + 0] = (c0.x > 0) ? (u0.x - c0.x) : -1;
    cst[t*9 + 1] = (c0.y > 0) ? (u0.y - c0.y) : -1;
    cst[t*9 + 2] = (c0.z > 0) ? (u0.z - c0.z) : -1;
    cst[t*9 + 3] = (c0.w > 0) ? (u0.w - c0.w) : -1;
    cst[t*9 + 4] = (c1.x > 0) ? (u1.x - c1.x) : -1;
    cst[t*9 + 5] = (c1.y > 0) ? (u1.y - c1.y) : -1;
    cst[t*9 + 6] = (c1.z > 0) ? (u1.z - c1.z) : -1;
    cst[t*9 + 7] = (c1.w > 0) ? (u1.w - c1.w) : -1;
  }
  __syncthreads();
  int lane = t & 63, wv = t >> 6;
  int l15 = lane & 15, q = lane >> 4;
  int SB = wv * 32;
  v8s a[8][2];
#pragma unroll
  for (int c = 0; c < 8; c++) {
#pragma unroll
    for (int mt = 0; mt < 2; mt++) {
      int site = SB + mt*16 + l15;
      int sp2 = cst[site*9 + c];
      v8s av = {0,0,0,0,0,0,0,0};
      if (sp2 >= 0) av = *(const v8s*)(afb + (size_t)sp2*32 + q*8);
      a[c][mt] = av;
    }
  }
  v4f acc[2][4];
#pragma unroll
  for (int i = 0; i < 2; i++)
#pragma unroll
    for (int j = 0; j < 4; j++) acc[i][j] = (v4f){0.f, 0.f, 0.f, 0.f};
#pragma unroll
  for (int c = 0; c < 8; c++) {
    v8s b[4];
#pragma unroll
    for (int nt = 0; nt < 4; nt++)
      b[nt] = *(const v8s*)&wlds[c*2048 + (nt*16 + l15)*32 + q*8];
#pragma unroll
    for (int mt = 0; mt < 2; mt++)
#pragma unroll
      for (int nt = 0; nt < 4; nt++)
        acc[mt][nt] = __builtin_amdgcn_mfma_f32_16x16x32_bf16(a[c][mt], b[nt], acc[mt][nt], 0, 0, 0);
  }
  float ss[4] = {0,0,0,0}, sq[4] = {0,0,0,0};
#pragma unroll
  for (int mt = 0; mt < 2; mt++) {
#pragma unroll
    for (int nt = 0; nt < 4; nt++) {
#pragma unroll
      for (int r = 0; r < 4; r++) {
        int sl = SB + mt*16 + q*4 + r;
        ushort_t h = f2b(acc[mt][nt][r]);
        float v = b2f(h);
        x1b[(size_t)okl[sl]*64 + nt*16 + l15] = h;
        ss[nt] += v; sq[nt] += v*v;
      }
    }
  }
#pragma unroll
  for (int nt = 0; nt < 4; nt++) {
    float v1 = ss[nt], v2 = sq[nt];
    v1 += __shfl_xor(v1, 16); v1 += __shfl_xor(v1, 32);
    v2 += __shfl_xor(v2, 16); v2 += __shfl_xor(v2, 32);
    if (lane < 16) { redS[wv][nt*16 + l15] = v1; redQ[wv][nt*16 + l15] = v2; }
  }
  __syncthreads();
  if (t < 64) {
    float s = redS[0][t] + redS[1][t] + redS[2][t] + redS[3][t];
    float qq = redQ[0][t] + redQ[1][t] + redQ[2][t] + redQ[3][t];
    int row = (blockIdx.x & 31) * 80;
    atomicAdd(&sp[row + t], s);
    atomicAdd(&qp[row + t], qq);
  }
}

// ---------------- MFMA conv (conv2/conv3): contiguous okey-grouped input ----------------
// xin/mprev are okey-grouped at THIS level: children of output site g are
// xin[(g*8+ch)*CSTRIDE ...] -- contiguous, no spatial decode on the read path.
// Output written okey-grouped for the NEXT level.
template <int CSTRIDE, int CIN_REAL, bool NINT, int NROW, int INSTR,
          int DO, int HO, int WO>
__global__ __launch_bounds__(256) void k_convm(
    const ushort_t* __restrict__ xin, const float* __restrict__ mprev,
    const ushort_t* __restrict__ wtg,
    const float* __restrict__ gam, const float* __restrict__ bet,
    const float* __restrict__ spin, const float* __restrict__ qpin,
    const void* __restrict__ ncnt, const float* __restrict__ npin,
    ushort_t* __restrict__ xout, float* __restrict__ osum, float* __restrict__ osq,
    float* __restrict__ mout, float* __restrict__ npart) {
  const int NCHUNK = CSTRIDE / 4;
  __shared__ __align__(16) float sc[CSTRIDE], sh[CSTRIDE];
  __shared__ float cmask[64*9];
  __shared__ int okl[64];
  __shared__ float redS[4][64], redQ[4][64];
  int t = threadIdx.x;
  if (t < CSTRIDE) {
    float scv = 0.f, shv = 0.f;
    if (t < CIN_REAL) {
      float n;
      if (NINT) n = fmaxf((float)((const int*)ncnt)[0], 1.0f);
      else {
        float nn = 0.f;
        for (int r = 0; r < 32; r++) nn += npin[r];
        n = fmaxf(nn, 1.0f);
      }
      float s1 = 0.f, q1 = 0.f;
      for (int r = 0; r < NROW; r++) { s1 += spin[r*INSTR + t]; q1 += qpin[r*INSTR + t]; }
      float mean = s1 / n;
      float var = q1 / n - mean * mean;
      float s = gam[t] * rsqrtf(var + EPS_);
      scv = s; shv = bet[t] - mean * s;
    }
    sc[t] = scv; sh[t] = shv;
  }
#pragma unroll
  for (int ii = 0; ii < 2; ii++) {
    int idx = t + ii*256;
    cmask[(idx >> 3)*9 + (idx & 7)] = mprev[(size_t)blockIdx.x * 512 + idx];
  }
  if (t < 64) okl[t] = okey<DO,HO,WO>(blockIdx.x * 64 + t);
  __syncthreads();
  int lane = t & 63, wv = t >> 6;
  int l15 = lane & 15, q = lane >> 4;
  int SB = (wv & 1) * 32, NB = (wv >> 1) * 64;
  size_t gbase = (size_t)blockIdx.x * 512;   // first child element row of this block
  v4f acc[2][4];
#pragma unroll
  for (int i = 0; i < 2; i++)
#pragma unroll
    for (int j = 0; j < 4; j++) acc[i][j] = (v4f){0.f, 0.f, 0.f, 0.f};
  uint4 rawN[2]; float mskN[2]; v8s bN[4];
#pragma unroll
  for (int mt = 0; mt < 2; mt++) {
    int site = SB + mt*16 + l15;
    rawN[mt] = *(const uint4*)(xin + (gbase + site*8) * CSTRIDE + q*8);
    mskN[mt] = cmask[site*9];
  }
#pragma unroll
  for (int nt = 0; nt < 4; nt++)
    bN[nt] = *(const v8s*)(wtg + (NB + nt*16 + l15)*32 + q*8);
#pragma unroll
  for (int c = 0; c < NCHUNK; c++) {
    uint4 raw[2] = {rawN[0], rawN[1]};
    float mskc[2] = {mskN[0], mskN[1]};
    v8s b[4] = {bN[0], bN[1], bN[2], bN[3]};
    if (c + 1 < NCHUNK) {
      int ch1 = ((c+1) * 32) / CSTRIDE;
      int cio1 = ((c+1) * 32) % CSTRIDE + q * 8;
#pragma unroll
      for (int mt = 0; mt < 2; mt++) {
        int site = SB + mt*16 + l15;
        rawN[mt] = *(const uint4*)(xin + (gbase + site*8 + ch1) * CSTRIDE + cio1);
        mskN[mt] = cmask[site*9 + ch1];
      }
#pragma unroll
      for (int nt = 0; nt < 4; nt++)
        bN[nt] = *(const v8s*)(wtg + (size_t)(c+1)*4096 + (NB + nt*16 + l15)*32 + q*8);
    }
    int cio = (c * 32) % CSTRIDE + q * 8;
    float4 sc0 = *(const float4*)&sc[cio];
    float4 sc1 = *(const float4*)&sc[cio + 4];
    float4 sh0 = *(const float4*)&sh[cio];
    float4 sh1 = *(const float4*)&sh[cio + 4];
    v8s a[2];
#pragma unroll
    for (int mt = 0; mt < 2; mt++) {
      int4 pk;
      pk.x = (int)bn2(raw[mt].x, sc0.x, sh0.x, sc0.y, sh0.y, mskc[mt]);
      pk.y = (int)bn2(raw[mt].y, sc0.z, sh0.z, sc0.w, sh0.w, mskc[mt]);
      pk.z = (int)bn2(raw[mt].z, sc1.x, sh1.x, sc1.y, sh1.y, mskc[mt]);
      pk.w = (int)bn2(raw[mt].w, sc1.z, sh1.z, sc1.w, sh1.w, mskc[mt]);
      a[mt] = *(v8s*)&pk;
    }
#pragma unroll
    for (int mt = 0; mt < 2; mt++)
#pragma unroll
      for (int nt = 0; nt < 4; nt++)
        acc[mt][nt] = __builtin_amdgcn_mfma_f32_16x16x32_bf16(a[mt], b[nt], acc[mt][nt], 0, 0, 0);
  }
  float ss[4] = {0,0,0,0}, sq[4] = {0,0,0,0};
#pragma unroll
  for (int mt = 0; mt < 2; mt++) {
#pragma unroll
    for (int nt = 0; nt < 4; nt++) {
#pragma unroll
      for (int r = 0; r < 4; r++) {
        int sl = SB + mt*16 + q*4 + r;
        ushort_t h = f2b(acc[mt][nt][r]);
        float v = b2f(h);
        xout[(size_t)okl[sl]*128 + NB + nt*16 + l15] = h;
        ss[nt] += v; sq[nt] += v*v;
      }
    }
  }
  if (t < 64) {
    bool act = false;
#pragma unroll
    for (int ch = 0; ch < 8; ch++) act |= (cmask[t*9 + ch] > 0.f);
    mout[okl[t]] = act ? 1.f : 0.f;
    unsigned long long bal = __ballot(act);
    if (t == 0) atomicAdd(&npart[blockIdx.x & 31], (float)__popcll(bal));
  }
#pragma unroll
  for (int nt = 0; nt < 4; nt++) {
    float v1 = ss[nt], v2 = sq[nt];
    v1 += __shfl_xor(v1, 16); v1 += __shfl_xor(v1, 32);
    v2 += __shfl_xor(v2, 16); v2 += __shfl_xor(v2, 32);
    if (lane < 16) { redS[wv][nt*16 + l15] = v1; redQ[wv][nt*16 + l15] = v2; }
  }
  __syncthreads();
  if (t < 128) {
    float s, qq;
    if (t < 64) { s = redS[0][t] + redS[1][t]; qq = redQ[0][t] + redQ[1][t]; }
    else        { s = redS[2][t-64] + redS[3][t-64]; qq = redQ[2][t-64] + redQ[3][t-64]; }
    int row = (blockIdx.x & 15) * 144;
    atomicAdd(&osum[row + t], s);
    atomicAdd(&osq[row + t], qq);
  }
}

// ---------------- final conv + sigmoid + mask (contiguous okey3-grouped input) ----------------
__global__ __launch_bounds__(256) void k_final(
    const ushort_t* __restrict__ x3b, const float* __restrict__ m3b,
    const float* __restrict__ w4, const float* __restrict__ gam,
    const float* __restrict__ bet, const float* __restrict__ spin,
    const float* __restrict__ qpin, const float* __restrict__ npin,
    float* __restrict__ out) {
  __shared__ float sc[128], sh[128];
  __shared__ float msk[8];
  __shared__ float red[256];
  int t = threadIdx.x;
  if (t < 128) {
    float nn = 0.f;
    for (int r = 0; r < 32; r++) nn += npin[r];
    float n = fmaxf(nn, 1.0f);
    float s1 = 0.f, q1 = 0.f;
    for (int r = 0; r < 16; r++) { s1 += spin[r*144 + t]; q1 += qpin[r*144 + t]; }
    float mean = s1 / n;
    float var = q1 / n - mean * mean;
    float s = gam[t] * rsqrtf(var + EPS_);
    sc[t] = s; sh[t] = bet[t] - mean * s;
  }
  int g = blockIdx.x;
  if (t < 8) msk[t] = m3b[g*8 + t];
  __syncthreads();
  float acc = 0.f;
#pragma unroll
  for (int ii = 0; ii < 4; ii++) {
    int k = t + ii*256;
    int ch = k >> 7, ci = k & 127;
    float v = b2f(x3b[(size_t)(g*8 + ch)*128 + ci]);
    v = v * sc[ci] + sh[ci];
    v = (v > 0.f ? v : LEAK_ * v) * msk[ch];
    acc += v * w4[k];
  }
  red[t] = acc;
  __syncthreads();
  if (t < 128) red[t] += red[t + 128];
  __syncthreads();
  if (t < 64) {
    float v = red[t] + red[t + 64];
#pragma unroll
    for (int off = 32; off > 0; off >>= 1) v += __shfl_down(v, off);
    if (t == 0) {
      float any = (msk[0] + msk[1] + msk[2] + msk[3] + msk[4] + msk[5] + msk[6] + msk[7]) > 0.f ? 1.f : 0.f;
      out[g] = any / (1.0f + expf(-v));
    }
  }
}

extern "C" void kernel_launch(void* const* d_in, const int* in_sizes, int n_in,
                              void* d_out, int out_size, void* d_ws, size_t ws_size,
                              hipStream_t stream) {
  (void)in_sizes; (void)n_in; (void)out_size; (void)ws_size;
  const float* feat = (const float*)d_in[0];
  const int*   crd  = (const int*)d_in[1];
  const float* w1 = (const float*)d_in[2];
  const float* g1 = (const float*)d_in[3];
  const float* b1 = (const float*)d_in[4];
  const float* w2 = (const float*)d_in[5];
  const float* g2 = (const float*)d_in[6];
  const float* b2 = (const float*)d_in[7];
  const float* w3 = (const float*)d_in[8];
  const float* g3 = (const float*)d_in[9];
  const float* b3 = (const float*)d_in[10];
  const float* w4 = (const float*)d_in[11];
  float* out = (float*)d_out;
  float* ws  = (float*)d_ws;

  int*      cnt    = (int*)(ws + OFF_CNT);
  float*    st     = ws + OFF_STATS;
  int*      cursor = (int*)(ws + OFF_CURSOR);
  int*      sorted = (int*)(ws + OFF_SORTED);
  int*      aklist = (int*)(ws + OFF_AKLIST);
  ushort_t* wt1g   = (ushort_t*)(ws + OFF_WT1);
  ushort_t* wt2g   = (ushort_t*)(ws + OFF_WT2);
  ushort_t* wt3g   = (ushort_t*)(ws + OFF_WT3);
  ushort_t* afb    = (ushort_t*)(ws + OFF_AFEATB);
  ushort_t* x1b    = (ushort_t*)(ws + OFF_X1B);
  ushort_t* x2b    = (ushort_t*)(ws + OFF_X2B);
  ushort_t* x3b    = (ushort_t*)(ws + OFF_X3B);
  float*    m1b    = ws + OFF_M1;
  float*    m2b    = ws + OFF_M2;
  float*    m3b    = ws + OFF_M3;
  ull_t*    pkctr  = (ull_t*)(st + ST_PK);
  int*      nactk  = (int*)(st + ST_PK);
  int*      nactp  = (int*)(st + ST_PK + 1);

  // zero only cnt; stats zeroed inside k_front
  hipMemsetAsync(cnt, 0, (size_t)NVOX * sizeof(int), stream);

  k_front<<<NB_COUNT + NB_PREPW + NB_STZ, 256, 0, stream>>>(
      crd, cnt, w1, w2, w3, wt1g, wt2g, wt3g, st);
  k_alloc<<<NVOX / 16384, 1024, 0, stream>>>(cnt, cursor, m1b, aklist,
                                             (int*)(st + ST_GCUR), pkctr);
  k_scatter<<<(PNUM + 255) / 256, 256, 0, stream>>>(crd, cursor, sorted);
  k_avg<<<(PNUM * 8) / 256 + 1, 256, 0, stream>>>(feat, sorted, cnt, cursor, aklist,
                                                  nactk, afb);
  k_conv1m<<<N1S / 128, 256, 0, stream>>>(afb, cnt, cursor, wt1g, x1b,
                                          st + ST_S1P, st + ST_Q1P);
  k_convm<64, 64, true, 32, 80, D2,H2,W2><<<N2S / 64, 256, 0, stream>>>(
      x1b, m1b, wt2g, g1, b1, st + ST_S1P, st + ST_Q1P, (const void*)nactp, nullptr,
      x2b, st + ST_S2P, st + ST_Q2P, m2b, st + ST_N2P);
  k_convm<128, 96, false, 16, 144, D3,H3,W3><<<N3S / 64, 256, 0, stream>>>(
      x2b, m2b, wt3g, g2, b2, st + ST_S2P, st + ST_Q2P, nullptr, st + ST_N2P,
      x3b, st + ST_S3P, st + ST_Q3P, m3b, st + ST_N3P);
  k_final<<<N4S, 256, 0, stream>>>(x3b, m3b, w4, g3, b3,
                                   st + ST_S3P, st + ST_Q3P, st + ST_N3P, out);
}

// Round 12
// 244.222 us; speedup vs baseline: 1.3201x; 1.0061x over previous
//
#include <hip/hip_runtime.h>
#include <math.h>

#define PNUM 300000
#define B_ 2
#define D0 144
#define H0 64
#define W0 160
#define NVOX (B_*D0*H0*W0)   // 2,949,120

#define D1 72
#define H1 32
#define W1 80
#define N1S (B_*D1*H1*W1)   // 368640

#define D2 36
#define H2 16
#define W2 40
#define N2S (B_*D2*H2*W2)   // 46080

#define D3 18
#define H3 8
#define W3 20
#define N3S (B_*D3*H3*W3)   // 5760

#define D4 9
#define H4 4
#define W4 10
#define N4S (B_*D4*H4*W4)   // 720

#define EPS_ 1e-4f
#define LEAK_ 0.2f

typedef __attribute__((ext_vector_type(8))) short v8s;
typedef __attribute__((ext_vector_type(4))) float v4f;

typedef unsigned short ushort_t;
typedef unsigned int uint_t;
typedef unsigned long long ull_t;

__device__ __forceinline__ ushort_t f2b(float f) {
  union { float f; uint_t u; } x; x.f = f;
  uint_t r = x.u + 0x7FFFu + ((x.u >> 16) & 1u);
  return (ushort_t)(r >> 16);
}
__device__ __forceinline__ float b2f(ushort_t h) {
  union { uint_t u; float f; } x; x.u = ((uint_t)h) << 16; return x.f;
}
__device__ __forceinline__ uint_t bn2(uint_t w, float s0, float h0, float s1, float h1,
                                      float msk) {
  float v0 = b2f((ushort_t)(w & 0xffff));
  float v1 = b2f((ushort_t)(w >> 16));
  v0 = fmaf(v0, s0, h0); v1 = fmaf(v1, s1, h1);
  v0 = fmaxf(v0, LEAK_ * v0) * msk;
  v1 = fmaxf(v1, LEAK_ * v1) * msk;
  return (uint_t)f2b(v0) | ((uint_t)f2b(v1) << 16);
}

template <int DD, int HH, int WW>
__device__ __forceinline__ int okey(int p) {
  int b = p / (DD*HH*WW); int r = p - b*(DD*HH*WW);
  int x = r / (HH*WW); r -= x*(HH*WW);
  int y = r / WW; int z = r - y*WW;
  return (((((b*(DD/2) + (x >> 1))*(HH/2) + (y >> 1))*(WW/2)) + (z >> 1)) << 3)
         | ((x & 1) << 2) | ((y & 1) << 1) | (z & 1);
}

// workspace layout (4-byte word offsets)
#define OFF_CNT     0          // NVOX ints
#define OFF_STATS   2949120    // 16384 words
#define OFF_CURSOR  2965504    // NVOX ints (after scatter: cursor = start + cnt)
#define OFF_DKLIST  5914624    // dup-key list (<=150K)
#define OFF_WT1     6514624
#define OFF_WT2     6522816
#define OFF_WT3     6555584
#define OFF_AFEATB  6621120    // 9.6M bf16 slots (scaled features)
#define OFF_X1B     11421120   // bf16, okey1-grouped
#define OFF_X2B     23217600   // bf16, okey2-grouped
#define OFF_X3B     26166720   // bf16, okey3-grouped
#define OFF_M1      26535360
#define OFF_M2      26904000
#define OFF_M3      26950080

#define ST_S1P  0        // [32][80]
#define ST_Q1P  2560
#define ST_S2P  5120     // [16][144]
#define ST_Q2P  7424
#define ST_S3P  9728
#define ST_Q3P  12032
#define ST_N2P  14336    // [32]
#define ST_N3P  14368    // [32]
#define ST_GCUR 14400
#define ST_PK   14404    // ull (lo=ndup, hi=nactp)

__device__ __forceinline__ int voxkey(int b, int x, int y, int z) {
  int p = ((b*D1 + (x >> 1))*H1 + (y >> 1))*W1 + (z >> 1);
  int oct = ((x & 1) << 2) | ((y & 1) << 1) | (z & 1);
  return p*8 + oct;
}

// ---------------- fused front-end: densify count + weight prep + stats zero ----------------
#define NB_COUNT 1172
#define NB_PREPW 832
#define NB_STZ   16
__global__ __launch_bounds__(256) void k_front(
    const int* __restrict__ coords, int* __restrict__ cnt,
    const float* __restrict__ w1, const float* __restrict__ w2,
    const float* __restrict__ w3,
    ushort_t* __restrict__ wt1, ushort_t* __restrict__ wt2,
    ushort_t* __restrict__ wt3, float* __restrict__ stz) {
  int bb = blockIdx.x, t = threadIdx.x;
  if (bb < NB_COUNT) {
    int i = bb * 256 + t;
    if (i < PNUM) {
      int4 c = *(const int4*)(coords + i*4);
      atomicAdd(&cnt[voxkey(c.x, c.y, c.z, c.w)], 1);
    }
  } else if (bb < NB_COUNT + NB_PREPW) {
    int idx = (bb - NB_COUNT) * 256 + t;
    if (idx < 16384) {
      int c = idx >> 11, r = idx & 2047;
      int co = r >> 5, kk = r & 31;
      wt1[idx] = f2b(w1[(c*32 + kk)*64 + co]);
    } else if (idx < 16384 + 65536) {
      int i = idx - 16384;
      int c = i >> 12, r = i & 4095;
      int co = r >> 5, kk = r & 31;
      int k = c*32 + kk;
      wt2[i] = (co < 96) ? f2b(w2[k*96 + co]) : 0;
    } else {
      int i = idx - 81920;
      int c = i >> 12, r = i & 4095;
      int co = r >> 5, kk = r & 31;
      int k = c*32 + kk;
      int ch = k >> 7, ci = k & 127;
      wt3[i] = (ci < 96) ? f2b(w3[(ch*96 + ci)*128 + co]) : 0;
    }
  } else {
    int off = ((bb - NB_COUNT - NB_PREPW) * 256 + t) * 4;
    *(float4*)(stz + off) = make_float4(0.f, 0.f, 0.f, 0.f);
  }
}

// ---------------- fused alloc + compaction: cursor, m1 (okey order), dklist ----------------
// 16384 keys (2048 parents) per block; combined 64-bit scan (slots hi, (pa<<16|dup) lo).
__global__ __launch_bounds__(1024) void k_alloc(const int* __restrict__ cnt,
                                                int* __restrict__ cursor,
                                                float* __restrict__ m1b,
                                                int* __restrict__ dklist,
                                                int* __restrict__ gcur,
                                                ull_t* __restrict__ pkctr) {
  __shared__ ull_t wsum[16];
  __shared__ int slotBase;
  __shared__ ull_t pkBase;
  int t = threadIdx.x;
  int idx0 = blockIdx.x * 16384 + t * 16;
  int c[16];
  int tsum = 0, dup = 0;
#pragma unroll
  for (int j = 0; j < 4; j++) {
    int4 cv = *(const int4*)(cnt + idx0 + j*4);
    c[j*4+0] = cv.x; c[j*4+1] = cv.y; c[j*4+2] = cv.z; c[j*4+3] = cv.w;
    tsum += cv.x + cv.y + cv.z + cv.w;
  }
#pragma unroll
  for (int j = 0; j < 16; j++) dup += (c[j] > 1) ? 1 : 0;
  uint_t m0 = 0, m1m = 0;
#pragma unroll
  for (int j = 0; j < 8; j++) { if (c[j] > 0) m0 |= (1u << j); }
#pragma unroll
  for (int j = 0; j < 8; j++) { if (c[8+j] > 0) m1m |= (1u << j); }
  int pa = ((m0 != 0) ? 1 : 0) + ((m1m != 0) ? 1 : 0);
  ull_t sv = ((ull_t)(uint_t)tsum << 32) | (ull_t)(uint_t)((pa << 16) | dup);
  int lane = t & 63, wid = t >> 6;
  ull_t incl = sv;
#pragma unroll
  for (int o = 1; o < 64; o <<= 1) {
    ull_t v = __shfl_up(incl, o);
    if (lane >= o) incl += v;
  }
  if (lane == 63) wsum[wid] = incl;
  __syncthreads();
  if (t == 0) {
    ull_t tot = 0;
#pragma unroll
    for (int w = 0; w < 16; w++) { ull_t v = wsum[w]; wsum[w] = tot; tot += v; }
    slotBase = atomicAdd(gcur, (int)(tot >> 32));
    uint_t pk = (uint_t)(tot & 0xffffffffULL);
    pkBase = atomicAdd(pkctr, ((ull_t)(pk >> 16) << 32) | (ull_t)(pk & 0xffff));
  }
  __syncthreads();
  ull_t excl = wsum[wid] + incl - sv;
  int st = slotBase + (int)(excl >> 32);
  uint_t pkl = (uint_t)(excl & 0xffffffffULL);
  int koff = (int)(pkBase & 0xffffffffULL) + (int)(pkl & 0xffff);
#pragma unroll
  for (int j = 0; j < 4; j++) {
    int4 sv2;
    sv2.x = st; st += c[j*4+0];
    sv2.y = st; st += c[j*4+1];
    sv2.z = st; st += c[j*4+2];
    sv2.w = st; st += c[j*4+3];
    *(int4*)(cursor + idx0 + j*4) = sv2;
  }
  int p0 = idx0 >> 3;
  m1b[okey<D1,H1,W1>(p0)]     = (m0 != 0) ? 1.f : 0.f;
  m1b[okey<D1,H1,W1>(p0 + 1)] = (m1m != 0) ? 1.f : 0.f;
#pragma unroll
  for (int j = 0; j < 16; j++)
    if (c[j] > 1) dklist[koff++] = idx0 + j;
}

// ---------------- scatter: write SCALED bf16 feature row into slot ----------------
// replaces index scatter + gathered averaging; cnt==1 slots are final afb values.
__global__ __launch_bounds__(256) void k_scatter(const int* __restrict__ coords,
                                                 const float* __restrict__ feat,
                                                 const int* __restrict__ cnt,
                                                 int* __restrict__ cursor,
                                                 ushort_t* __restrict__ afb) {
  int i = blockIdx.x * 256 + threadIdx.x;
  if (i >= PNUM) return;
  int4 c = *(const int4*)(coords + i*4);
  int key = voxkey(c.x, c.y, c.z, c.w);
  int slot = atomicAdd(&cursor[key], 1);
  float inv = 1.f / (float)cnt[key];
  const float4* fp = (const float4*)(feat + (size_t)i * 32);
  uint_t o[16];
#pragma unroll
  for (int q = 0; q < 8; q++) {
    float4 v = fp[q];
    o[q*2]   = (uint_t)f2b(v.x*inv) | ((uint_t)f2b(v.y*inv) << 16);
    o[q*2+1] = (uint_t)f2b(v.z*inv) | ((uint_t)f2b(v.w*inv) << 16);
  }
  uint4* dst = (uint4*)(afb + (size_t)slot * 32);
  dst[0] = make_uint4(o[0], o[1], o[2], o[3]);
  dst[1] = make_uint4(o[4], o[5], o[6], o[7]);
  dst[2] = make_uint4(o[8], o[9], o[10], o[11]);
  dst[3] = make_uint4(o[12], o[13], o[14], o[15]);
}

// ---------------- dup-key averaging: sum the (scaled) slots into slot s0 ----------------
__global__ __launch_bounds__(256) void k_davg(const int* __restrict__ cnt,
                                              const int* __restrict__ cursor,
                                              const int* __restrict__ dklist,
                                              const int* __restrict__ ndup,
                                              ushort_t* __restrict__ afb) {
  int gid = blockIdx.x * 256 + threadIdx.x;
  int j = gid >> 3;
  if (j >= ndup[0]) return;
  int key = dklist[j];
  int c = cnt[key];
  int s0 = cursor[key] - c;
  int q = (gid & 7) * 4;
  float a0 = 0.f, a1 = 0.f, a2 = 0.f, a3 = 0.f;
  for (int i = 0; i < c; i++) {
    uint2 u = *(const uint2*)(afb + (size_t)(s0 + i) * 32 + q);
    a0 += b2f((ushort_t)(u.x & 0xffff)); a1 += b2f((ushort_t)(u.x >> 16));
    a2 += b2f((ushort_t)(u.y & 0xffff)); a3 += b2f((ushort_t)(u.y >> 16));
  }
  uint2 o;
  o.x = (uint_t)f2b(a0) | ((uint_t)f2b(a1) << 16);
  o.y = (uint_t)f2b(a2) | ((uint_t)f2b(a3) << 16);
  *(uint2*)(afb + (size_t)s0 * 32 + q) = o;
}

// ---------------- MFMA conv1: predicated stores (skip inactive parents) ----------------
__global__ __launch_bounds__(256) void k_conv1m(
    const ushort_t* __restrict__ afb, const int* __restrict__ cnt,
    const int* __restrict__ cursor, const ushort_t* __restrict__ wtg,
    ushort_t* __restrict__ x1b, float* __restrict__ sp, float* __restrict__ qp) {
  __shared__ __align__(16) ushort_t wlds[16384];
  __shared__ int cst[128*9];
  __shared__ int okl[128];
  __shared__ int pact[128];
  __shared__ float redS[4][64], redQ[4][64];
  int t = threadIdx.x;
#pragma unroll
  for (int i = 0; i < 8; i++)
    ((uint4*)wlds)[t + i*256] = ((const uint4*)wtg)[t + i*256];
  if (t < 128) {
    int p = blockIdx.x * 128 + t;
    okl[t] = okey<D1,H1,W1>(p);
    const int4* cp = (const int4*)(cnt + (size_t)p*8);
    const int4* up = (const int4*)(cursor + (size_t)p*8);
    int4 c0 = cp[0], c1 = cp[1], u0 = up[0], u1 = up[1];
    cst[t*9 + 0] = (c0.x > 0) ? (u0.x - c0.x) : -1;
    cst[t*9 + 1] = (c0.y > 0) ? (u0.y - c0.y) : -1;
    cst[t*9 + 2] = (c0.z > 0) ? (u0.z - c0.z) : -1;
    cst[t*9 + 3] = (c0.w > 0) ? (u0.w - c0.w) : -1;
    cst[t*9 + 4] = (c1.x > 0) ? (u1.x - c1.x) : -1;
    cst[t*9 + 5] = (c1.y > 0) ? (u1.y - c1.y) : -1;
    cst[t*9 + 6] = (c1.z > 0) ? (u1.z - c1.z) : -1;
    cst[t*9 + 7] = (c1.w > 0) ? (u1.w - c1.w) : -1;
    pact[t] = (c0.x + c0.y + c0.z + c0.w + c1.x + c1.y + c1.z + c1.w) > 0 ? 1 : 0;
  }
  __syncthreads();
  int lane = t & 63, wv = t >> 6;
  int l15 = lane & 15, q = lane >> 4;
  int SB = wv * 32;
  v8s a[8][2];
#pragma unroll
  for (int c = 0; c < 8; c++) {
#pragma unroll
    for (int mt = 0; mt < 2; mt++) {
      int site = SB + mt*16 + l15;
      int sp2 = cst[site*9 + c];
      v8s av = {0,0,0,0,0,0,0,0};
      if (sp2 >= 0) av = *(const v8s*)(afb + (size_t)sp2*32 + q*8);
      a[c][mt] = av;
    }
  }
  v4f acc[2][4];
#pragma unroll
  for (int i = 0; i < 2; i++)
#pragma unroll
    for (int j = 0; j < 4; j++) acc[i][j] = (v4f){0.f, 0.f, 0.f, 0.f};
#pragma unroll
  for (int c = 0; c < 8; c++) {
    v8s b[4];
#pragma unroll
    for (int nt = 0; nt < 4; nt++)
      b[nt] = *(const v8s*)&wlds[c*2048 + (nt*16 + l15)*32 + q*8];
#pragma unroll
    for (int mt = 0; mt < 2; mt++)
#pragma unroll
      for (int nt = 0; nt < 4; nt++)
        acc[mt][nt] = __builtin_amdgcn_mfma_f32_16x16x32_bf16(a[c][mt], b[nt], acc[mt][nt], 0, 0, 0);
  }
  float ss[4] = {0,0,0,0}, sq[4] = {0,0,0,0};
#pragma unroll
  for (int mt = 0; mt < 2; mt++) {
#pragma unroll
    for (int nt = 0; nt < 4; nt++) {
#pragma unroll
      for (int r = 0; r < 4; r++) {
        int sl = SB + mt*16 + q*4 + r;
        ushort_t h = f2b(acc[mt][nt][r]);
        float v = b2f(h);
        if (pact[sl]) x1b[(size_t)okl[sl]*64 + nt*16 + l15] = h;  // inactive: consumer masks
        ss[nt] += v; sq[nt] += v*v;
      }
    }
  }
#pragma unroll
  for (int nt = 0; nt < 4; nt++) {
    float v1 = ss[nt], v2 = sq[nt];
    v1 += __shfl_xor(v1, 16); v1 += __shfl_xor(v1, 32);
    v2 += __shfl_xor(v2, 16); v2 += __shfl_xor(v2, 32);
    if (lane < 16) { redS[wv][nt*16 + l15] = v1; redQ[wv][nt*16 + l15] = v2; }
  }
  __syncthreads();
  if (t < 64) {
    float s = redS[0][t] + redS[1][t] + redS[2][t] + redS[3][t];
    float qq = redQ[0][t] + redQ[1][t] + redQ[2][t] + redQ[3][t];
    int row = (blockIdx.x & 31) * 80;
    atomicAdd(&sp[row + t], s);
    atomicAdd(&qp[row + t], qq);
  }
}

// ---------------- MFMA conv (conv2/conv3): predicated A-loads on cmask ----------------
template <int CSTRIDE, int CIN_REAL, bool NINT, int NROW, int INSTR,
          int DO, int HO, int WO>
__global__ __launch_bounds__(256) void k_convm(
    const ushort_t* __restrict__ xin, const float* __restrict__ mprev,
    const ushort_t* __restrict__ wtg,
    const float* __restrict__ gam, const float* __restrict__ bet,
    const float* __restrict__ spin, const float* __restrict__ qpin,
    const void* __restrict__ ncnt, const float* __restrict__ npin,
    ushort_t* __restrict__ xout, float* __restrict__ osum, float* __restrict__ osq,
    float* __restrict__ mout, float* __restrict__ npart) {
  const int NCHUNK = CSTRIDE / 4;
  __shared__ __align__(16) float sc[CSTRIDE], sh[CSTRIDE];
  __shared__ float cmask[64*9];
  __shared__ int okl[64];
  __shared__ float redS[4][64], redQ[4][64];
  int t = threadIdx.x;
  if (t < CSTRIDE) {
    float scv = 0.f, shv = 0.f;
    if (t < CIN_REAL) {
      float n;
      if (NINT) n = fmaxf((float)((const int*)ncnt)[0], 1.0f);
      else {
        float nn = 0.f;
        for (int r = 0; r < 32; r++) nn += npin[r];
        n = fmaxf(nn, 1.0f);
      }
      float s1 = 0.f, q1 = 0.f;
      for (int r = 0; r < NROW; r++) { s1 += spin[r*INSTR + t]; q1 += qpin[r*INSTR + t]; }
      float mean = s1 / n;
      float var = q1 / n - mean * mean;
      float s = gam[t] * rsqrtf(var + EPS_);
      scv = s; shv = bet[t] - mean * s;
    }
    sc[t] = scv; sh[t] = shv;
  }
#pragma unroll
  for (int ii = 0; ii < 2; ii++) {
    int idx = t + ii*256;
    cmask[(idx >> 3)*9 + (idx & 7)] = mprev[(size_t)blockIdx.x * 512 + idx];
  }
  if (t < 64) okl[t] = okey<DO,HO,WO>(blockIdx.x * 64 + t);
  __syncthreads();
  int lane = t & 63, wv = t >> 6;
  int l15 = lane & 15, q = lane >> 4;
  int SB = (wv & 1) * 32, NB = (wv >> 1) * 64;
  size_t gbase = (size_t)blockIdx.x * 512;
  v4f acc[2][4];
#pragma unroll
  for (int i = 0; i < 2; i++)
#pragma unroll
    for (int j = 0; j < 4; j++) acc[i][j] = (v4f){0.f, 0.f, 0.f, 0.f};
  uint4 rawN[2]; float mskN[2]; v8s bN[4];
#pragma unroll
  for (int mt = 0; mt < 2; mt++) {
    int site = SB + mt*16 + l15;
    float m = cmask[site*9];
    uint4 rv = make_uint4(0, 0, 0, 0);
    if (m > 0.f) rv = *(const uint4*)(xin + (gbase + site*8) * CSTRIDE + q*8);
    rawN[mt] = rv; mskN[mt] = m;
  }
#pragma unroll
  for (int nt = 0; nt < 4; nt++)
    bN[nt] = *(const v8s*)(wtg + (NB + nt*16 + l15)*32 + q*8);
#pragma unroll
  for (int c = 0; c < NCHUNK; c++) {
    uint4 raw[2] = {rawN[0], rawN[1]};
    float mskc[2] = {mskN[0], mskN[1]};
    v8s b[4] = {bN[0], bN[1], bN[2], bN[3]};
    if (c + 1 < NCHUNK) {
      int ch1 = ((c+1) * 32) / CSTRIDE;
      int cio1 = ((c+1) * 32) % CSTRIDE + q * 8;
#pragma unroll
      for (int mt = 0; mt < 2; mt++) {
        int site = SB + mt*16 + l15;
        float m = cmask[site*9 + ch1];
        uint4 rv = make_uint4(0, 0, 0, 0);
        if (m > 0.f) rv = *(const uint4*)(xin + (gbase + site*8 + ch1) * CSTRIDE + cio1);
        rawN[mt] = rv; mskN[mt] = m;
      }
#pragma unroll
      for (int nt = 0; nt < 4; nt++)
        bN[nt] = *(const v8s*)(wtg + (size_t)(c+1)*4096 + (NB + nt*16 + l15)*32 + q*8);
    }
    int cio = (c * 32) % CSTRIDE + q * 8;
    float4 sc0 = *(const float4*)&sc[cio];
    float4 sc1 = *(const float4*)&sc[cio + 4];
    float4 sh0 = *(const float4*)&sh[cio];
    float4 sh1 = *(const float4*)&sh[cio + 4];
    v8s a[2];
#pragma unroll
    for (int mt = 0; mt < 2; mt++) {
      int4 pk;
      pk.x = (int)bn2(raw[mt].x, sc0.x, sh0.x, sc0.y, sh0.y, mskc[mt]);
      pk.y = (int)bn2(raw[mt].y, sc0.z, sh0.z, sc0.w, sh0.w, mskc[mt]);
      pk.z = (int)bn2(raw[mt].z, sc1.x, sh1.x, sc1.y, sh1.y, mskc[mt]);
      pk.w = (int)bn2(raw[mt].w, sc1.z, sh1.z, sc1.w, sh1.w, mskc[mt]);
      a[mt] = *(v8s*)&pk;
    }
#pragma unroll
    for (int mt = 0; mt < 2; mt++)
#pragma unroll
      for (int nt = 0; nt < 4; nt++)
        acc[mt][nt] = __builtin_amdgcn_mfma_f32_16x16x32_bf16(a[mt], b[nt], acc[mt][nt], 0, 0, 0);
  }
  float ss[4] = {0,0,0,0}, sq[4] = {0,0,0,0};
#pragma unroll
  for (int mt = 0; mt < 2; mt++) {
#pragma unroll
    for (int nt = 0; nt < 4; nt++) {
#pragma unroll
      for (int r = 0; r < 4; r++) {
        int sl = SB + mt*16 + q*4 + r;
        ushort_t h = f2b(acc[mt][nt][r]);
        float v = b2f(h);
        xout[(size_t)okl[sl]*128 + NB + nt*16 + l15] = h;
        ss[nt] += v; sq[nt] += v*v;
      }
    }
  }
  if (t < 64) {
    bool act = false;
#pragma unroll
    for (int ch = 0; ch < 8; ch++) act |= (cmask[t*9 + ch] > 0.f);
    mout[okl[t]] = act ? 1.f : 0.f;
    unsigned long long bal = __ballot(act);
    if (t == 0) atomicAdd(&npart[blockIdx.x & 31], (float)__popcll(bal));
  }
#pragma unroll
  for (int nt = 0; nt < 4; nt++) {
    float v1 = ss[nt], v2 = sq[nt];
    v1 += __shfl_xor(v1, 16); v1 += __shfl_xor(v1, 32);
    v2 += __shfl_xor(v2, 16); v2 += __shfl_xor(v2, 32);
    if (lane < 16) { redS[wv][nt*16 + l15] = v1; redQ[wv][nt*16 + l15] = v2; }
  }
  __syncthreads();
  if (t < 128) {
    float s, qq;
    if (t < 64) { s = redS[0][t] + redS[1][t]; qq = redQ[0][t] + redQ[1][t]; }
    else        { s = redS[2][t-64] + redS[3][t-64]; qq = redQ[2][t-64] + redQ[3][t-64]; }
    int row = (blockIdx.x & 15) * 144;
    atomicAdd(&osum[row + t], s);
    atomicAdd(&osq[row + t], qq);
  }
}

// ---------------- final conv + sigmoid + mask ----------------
__global__ __launch_bounds__(256) void k_final(
    const ushort_t* __restrict__ x3b, const float* __restrict__ m3b,
    const float* __restrict__ w4, const float* __restrict__ gam,
    const float* __restrict__ bet, const float* __restrict__ spin,
    const float* __restrict__ qpin, const float* __restrict__ npin,
    float* __restrict__ out) {
  __shared__ float sc[128], sh[128];
  __shared__ float msk[8];
  __shared__ float red[256];
  int t = threadIdx.x;
  if (t < 128) {
    float nn = 0.f;
    for (int r = 0; r < 32; r++) nn += npin[r];
    float n = fmaxf(nn, 1.0f);
    float s1 = 0.f, q1 = 0.f;
    for (int r = 0; r < 16; r++) { s1 += spin[r*144 + t]; q1 += qpin[r*144 + t]; }
    float mean = s1 / n;
    float var = q1 / n - mean * mean;
    float s = gam[t] * rsqrtf(var + EPS_);
    sc[t] = s; sh[t] = bet[t] - mean * s;
  }
  int g = blockIdx.x;
  if (t < 8) msk[t] = m3b[g*8 + t];
  __syncthreads();
  float acc = 0.f;
#pragma unroll
  for (int ii = 0; ii < 4; ii++) {
    int k = t + ii*256;
    int ch = k >> 7, ci = k & 127;
    float v = b2f(x3b[(size_t)(g*8 + ch)*128 + ci]);
    v = v * sc[ci] + sh[ci];
    v = (v > 0.f ? v : LEAK_ * v) * msk[ch];
    acc += v * w4[k];
  }
  red[t] = acc;
  __syncthreads();
  if (t < 128) red[t] += red[t + 128];
  __syncthreads();
  if (t < 64) {
    float v = red[t] + red[t + 64];
#pragma unroll
    for (int off = 32; off > 0; off >>= 1) v += __shfl_down(v, off);
    if (t == 0) {
      float any = (msk[0] + msk[1] + msk[2] + msk[3] + msk[4] + msk[5] + msk[6] + msk[7]) > 0.f ? 1.f : 0.f;
      out[g] = any / (1.0f + expf(-v));
    }
  }
}

extern "C" void kernel_launch(void* const* d_in, const int* in_sizes, int n_in,
                              void* d_out, int out_size, void* d_ws, size_t ws_size,
                              hipStream_t stream) {
  (void)in_sizes; (void)n_in; (void)out_size; (void)ws_size;
  const float* feat = (const float*)d_in[0];
  const int*   crd  = (const int*)d_in[1];
  const float* w1 = (const float*)d_in[2];
  const float* g1 = (const float*)d_in[3];
  const float* b1 = (const float*)d_in[4];
  const float* w2 = (const float*)d_in[5];
  const float* g2 = (const float*)d_in[6];
  const float* b2 = (const float*)d_in[7];
  const float* w3 = (const float*)d_in[8];
  const float* g3 = (const float*)d_in[9];
  const float* b3 = (const float*)d_in[10];
  const float* w4 = (const float*)d_in[11];
  float* out = (float*)d_out;
  float* ws  = (float*)d_ws;

  int*      cnt    = (int*)(ws + OFF_CNT);
  float*    st     = ws + OFF_STATS;
  int*      cursor = (int*)(ws + OFF_CURSOR);
  int*      dklist = (int*)(ws + OFF_DKLIST);
  ushort_t* wt1g   = (ushort_t*)(ws + OFF_WT1);
  ushort_t* wt2g   = (ushort_t*)(ws + OFF_WT2);
  ushort_t* wt3g   = (ushort_t*)(ws + OFF_WT3);
  ushort_t* afb    = (ushort_t*)(ws + OFF_AFEATB);
  ushort_t* x1b    = (ushort_t*)(ws + OFF_X1B);
  ushort_t* x2b    = (ushort_t*)(ws + OFF_X2B);
  ushort_t* x3b    = (ushort_t*)(ws + OFF_X3B);
  float*    m1b    = ws + OFF_M1;
  float*    m2b    = ws + OFF_M2;
  float*    m3b    = ws + OFF_M3;
  ull_t*    pkctr  = (ull_t*)(st + ST_PK);
  int*      ndup   = (int*)(st + ST_PK);
  int*      nactp  = (int*)(st + ST_PK + 1);

  hipMemsetAsync(cnt, 0, (size_t)NVOX * sizeof(int), stream);

  k_front<<<NB_COUNT + NB_PREPW + NB_STZ, 256, 0, stream>>>(
      crd, cnt, w1, w2, w3, wt1g, wt2g, wt3g, st);
  k_alloc<<<NVOX / 16384, 1024, 0, stream>>>(cnt, cursor, m1b, dklist,
                                             (int*)(st + ST_GCUR), pkctr);
  k_scatter<<<(PNUM + 255) / 256, 256, 0, stream>>>(crd, feat, cnt, cursor, afb);
  k_davg<<<4688, 256, 0, stream>>>(cnt, cursor, dklist, ndup, afb);
  k_conv1m<<<N1S / 128, 256, 0, stream>>>(afb, cnt, cursor, wt1g, x1b,
                                          st + ST_S1P, st + ST_Q1P);
  k_convm<64, 64, true, 32, 80, D2,H2,W2><<<N2S / 64, 256, 0, stream>>>(
      x1b, m1b, wt2g, g1, b1, st + ST_S1P, st + ST_Q1P, (const void*)nactp, nullptr,
      x2b, st + ST_S2P, st + ST_Q2P, m2b, st + ST_N2P);
  k_convm<128, 96, false, 16, 144, D3,H3,W3><<<N3S / 64, 256, 0, stream>>>(
      x2b, m2b, wt3g, g2, b2, st + ST_S2P, st + ST_Q2P, nullptr, st + ST_N2P,
      x3b, st + ST_S3P, st + ST_Q3P, m3b, st + ST_N3P);
  k_final<<<N4S, 256, 0, stream>>>(x3b, m3b, w4, g3, b3,
                                   st + ST_S3P, st + ST_Q3P, st + ST_N3P, out);
}

// Round 13
// 241.753 us; speedup vs baseline: 1.3336x; 1.0102x over previous
//
#include <hip/hip_runtime.h>
#include <math.h>

#define PNUM 300000
#define B_ 2
#define D0 144
#define H0 64
#define W0 160
#define NVOX (B_*D0*H0*W0)   // 2,949,120

#define D1 72
#define H1 32
#define W1 80
#define N1S (B_*D1*H1*W1)   // 368640

#define D2 36
#define H2 16
#define W2 40
#define N2S (B_*D2*H2*W2)   // 46080

#define D3 18
#define H3 8
#define W3 20
#define N3S (B_*D3*H3*W3)   // 5760

#define D4 9
#define H4 4
#define W4 10
#define N4S (B_*D4*H4*W4)   // 720

#define EPS_ 1e-4f
#define LEAK_ 0.2f

typedef __attribute__((ext_vector_type(8))) short v8s;
typedef __attribute__((ext_vector_type(4))) float v4f;

typedef unsigned short ushort_t;
typedef unsigned int uint_t;
typedef unsigned long long ull_t;

__device__ __forceinline__ ushort_t f2b(float f) {
  union { float f; uint_t u; } x; x.f = f;
  uint_t r = x.u + 0x7FFFu + ((x.u >> 16) & 1u);
  return (ushort_t)(r >> 16);
}
__device__ __forceinline__ float b2f(ushort_t h) {
  union { uint_t u; float f; } x; x.u = ((uint_t)h) << 16; return x.f;
}
__device__ __forceinline__ uint_t bn2(uint_t w, float s0, float h0, float s1, float h1,
                                      float msk) {
  float v0 = b2f((ushort_t)(w & 0xffff));
  float v1 = b2f((ushort_t)(w >> 16));
  v0 = fmaf(v0, s0, h0); v1 = fmaf(v1, s1, h1);
  v0 = fmaxf(v0, LEAK_ * v0) * msk;
  v1 = fmaxf(v1, LEAK_ * v1) * msk;
  return (uint_t)f2b(v0) | ((uint_t)f2b(v1) << 16);
}

template <int DD, int HH, int WW>
__device__ __forceinline__ int okey(int p) {
  int b = p / (DD*HH*WW); int r = p - b*(DD*HH*WW);
  int x = r / (HH*WW); r -= x*(HH*WW);
  int y = r / WW; int z = r - y*WW;
  return (((((b*(DD/2) + (x >> 1))*(HH/2) + (y >> 1))*(WW/2)) + (z >> 1)) << 3)
         | ((x & 1) << 2) | ((y & 1) << 1) | (z & 1);
}

// workspace layout (4-byte word offsets)
#define OFF_CNT     0          // NVOX ints
#define OFF_STATS   2949120    // 16384 words
#define OFF_CURSOR  2965504    // NVOX ints (after scatter: cursor = start + cnt)
#define OFF_WT1     6514624
#define OFF_WT2     6522816
#define OFF_WT3     6555584
#define OFF_AFEATB  6621120    // 9.6M bf16 slots (scaled features)
#define OFF_X1B     11421120   // bf16, okey1-grouped
#define OFF_X2B     23217600   // bf16, okey2-grouped
#define OFF_X3B     26166720   // bf16, okey3-grouped
#define OFF_M1      26535360
#define OFF_M2      26904000
#define OFF_M3      26950080

#define ST_S1P  0        // [32][80]
#define ST_Q1P  2560
#define ST_S2P  5120     // [16][144]
#define ST_Q2P  7424
#define ST_S3P  9728
#define ST_Q3P  12032
#define ST_N2P  14336    // [32]
#define ST_N3P  14368    // [32]
#define ST_GCUR 14400
#define ST_PK   14404    // int: nactp (active L1 sites)

__device__ __forceinline__ int voxkey(int b, int x, int y, int z) {
  int p = ((b*D1 + (x >> 1))*H1 + (y >> 1))*W1 + (z >> 1);
  int oct = ((x & 1) << 2) | ((y & 1) << 1) | (z & 1);
  return p*8 + oct;
}

// ---------------- fused front-end: densify count + weight prep + stats zero ----------------
#define NB_COUNT 1172
#define NB_PREPW 832
#define NB_STZ   16
__global__ __launch_bounds__(256) void k_front(
    const int* __restrict__ coords, int* __restrict__ cnt,
    const float* __restrict__ w1, const float* __restrict__ w2,
    const float* __restrict__ w3,
    ushort_t* __restrict__ wt1, ushort_t* __restrict__ wt2,
    ushort_t* __restrict__ wt3, float* __restrict__ stz) {
  int bb = blockIdx.x, t = threadIdx.x;
  if (bb < NB_COUNT) {
    int i = bb * 256 + t;
    if (i < PNUM) {
      int4 c = *(const int4*)(coords + i*4);
      atomicAdd(&cnt[voxkey(c.x, c.y, c.z, c.w)], 1);
    }
  } else if (bb < NB_COUNT + NB_PREPW) {
    int idx = (bb - NB_COUNT) * 256 + t;
    if (idx < 16384) {
      int c = idx >> 11, r = idx & 2047;
      int co = r >> 5, kk = r & 31;
      wt1[idx] = f2b(w1[(c*32 + kk)*64 + co]);
    } else if (idx < 16384 + 65536) {
      int i = idx - 16384;
      int c = i >> 12, r = i & 4095;
      int co = r >> 5, kk = r & 31;
      int k = c*32 + kk;
      wt2[i] = (co < 96) ? f2b(w2[k*96 + co]) : 0;
    } else {
      int i = idx - 81920;
      int c = i >> 12, r = i & 4095;
      int co = r >> 5, kk = r & 31;
      int k = c*32 + kk;
      int ch = k >> 7, ci = k & 127;
      wt3[i] = (ci < 96) ? f2b(w3[(ch*96 + ci)*128 + co]) : 0;
    }
  } else {
    int off = ((bb - NB_COUNT - NB_PREPW) * 256 + t) * 4;
    *(float4*)(stz + off) = make_float4(0.f, 0.f, 0.f, 0.f);
  }
}

// ---------------- alloc: cursor + m1 (okey order) + nactp ----------------
// 16384 keys (2048 parents) per block; slot scan; 2 atomics/block.
__global__ __launch_bounds__(1024) void k_alloc(const int* __restrict__ cnt,
                                                int* __restrict__ cursor,
                                                float* __restrict__ m1b,
                                                int* __restrict__ gcur,
                                                int* __restrict__ nactp) {
  __shared__ int wsum[16];
  __shared__ int wpa[16];
  __shared__ int blockBase;
  int t = threadIdx.x;
  int idx0 = blockIdx.x * 16384 + t * 16;
  int c[16];
  int tsum = 0;
#pragma unroll
  for (int j = 0; j < 4; j++) {
    int4 cv = *(const int4*)(cnt + idx0 + j*4);
    c[j*4+0] = cv.x; c[j*4+1] = cv.y; c[j*4+2] = cv.z; c[j*4+3] = cv.w;
    tsum += cv.x + cv.y + cv.z + cv.w;
  }
  uint_t m0 = 0, m1m = 0;
#pragma unroll
  for (int j = 0; j < 8; j++) { if (c[j] > 0) m0 |= (1u << j); }
#pragma unroll
  for (int j = 0; j < 8; j++) { if (c[8+j] > 0) m1m |= (1u << j); }
  int pa = ((m0 != 0) ? 1 : 0) + ((m1m != 0) ? 1 : 0);
  int lane = t & 63, wid = t >> 6;
  int incl = tsum;
#pragma unroll
  for (int o = 1; o < 64; o <<= 1) {
    int v = __shfl_up(incl, o);
    if (lane >= o) incl += v;
  }
  int pw = pa;
#pragma unroll
  for (int o = 1; o < 64; o <<= 1) pw += __shfl_xor(pw, o);
  if (lane == 63) wsum[wid] = incl;
  if (lane == 0) wpa[wid] = pw;
  __syncthreads();
  if (t == 0) {
    int tot = 0, ptot = 0;
#pragma unroll
    for (int w = 0; w < 16; w++) { int v = wsum[w]; wsum[w] = tot; tot += v; ptot += wpa[w]; }
    blockBase = atomicAdd(gcur, tot);
    atomicAdd(nactp, ptot);
  }
  __syncthreads();
  int st = blockBase + wsum[wid] + incl - tsum;
#pragma unroll
  for (int j = 0; j < 4; j++) {
    int4 sv2;
    sv2.x = st; st += c[j*4+0];
    sv2.y = st; st += c[j*4+1];
    sv2.z = st; st += c[j*4+2];
    sv2.w = st; st += c[j*4+3];
    *(int4*)(cursor + idx0 + j*4) = sv2;
  }
  int p0 = idx0 >> 3;
  m1b[okey<D1,H1,W1>(p0)]     = (m0 != 0) ? 1.f : 0.f;
  m1b[okey<D1,H1,W1>(p0 + 1)] = (m1m != 0) ? 1.f : 0.f;
}

// ---------------- scatter: write SCALED bf16 feature row into slot ----------------
__global__ __launch_bounds__(256) void k_scatter(const int* __restrict__ coords,
                                                 const float* __restrict__ feat,
                                                 const int* __restrict__ cnt,
                                                 int* __restrict__ cursor,
                                                 ushort_t* __restrict__ afb) {
  int i = blockIdx.x * 256 + threadIdx.x;
  if (i >= PNUM) return;
  int4 c = *(const int4*)(coords + i*4);
  int key = voxkey(c.x, c.y, c.z, c.w);
  int slot = atomicAdd(&cursor[key], 1);
  float inv = 1.f / (float)cnt[key];
  const float4* fp = (const float4*)(feat + (size_t)i * 32);
  uint_t o[16];
#pragma unroll
  for (int q = 0; q < 8; q++) {
    float4 v = fp[q];
    o[q*2]   = (uint_t)f2b(v.x*inv) | ((uint_t)f2b(v.y*inv) << 16);
    o[q*2+1] = (uint_t)f2b(v.z*inv) | ((uint_t)f2b(v.w*inv) << 16);
  }
  uint4* dst = (uint4*)(afb + (size_t)slot * 32);
  dst[0] = make_uint4(o[0], o[1], o[2], o[3]);
  dst[1] = make_uint4(o[4], o[5], o[6], o[7]);
  dst[2] = make_uint4(o[8], o[9], o[10], o[11]);
  dst[3] = make_uint4(o[12], o[13], o[14], o[15]);
}

// ---------------- MFMA conv1: okey-ordered blocks (coalesced stores), inline dup-avg ----------------
// block owns 128 consecutive okeys; descriptors decoded via inverse okey (scattered
// 16B loads, cheap); stores fully contiguous; stats red arrays overlay dead weight LDS.
__global__ __launch_bounds__(256) void k_conv1m(
    const ushort_t* __restrict__ afb, const int* __restrict__ cnt,
    const int* __restrict__ cursor, const ushort_t* __restrict__ wtg,
    ushort_t* __restrict__ x1b, float* __restrict__ sp, float* __restrict__ qp) {
  __shared__ __align__(16) ushort_t wlds[16384];   // 32 KB; reused for stats reduce
  __shared__ int cst[128*9];
  __shared__ ushort_t ccn[128*9];
  __shared__ int pact[128];
  int t = threadIdx.x;
#pragma unroll
  for (int i = 0; i < 8; i++)
    ((uint4*)wlds)[t + i*256] = ((const uint4*)wtg)[t + i*256];
  if (t < 128) {
    int ok = blockIdx.x * 128 + t;
    int oct = ok & 7, qp2 = ok >> 3;
    int b = qp2 / (D2*H2*W2); int r = qp2 - b*(D2*H2*W2);
    int x2 = r / (H2*W2); r -= x2*(H2*W2);
    int y2 = r / W2; int z2 = r - y2*W2;
    int x = 2*x2 + ((oct >> 2) & 1);
    int y = 2*y2 + ((oct >> 1) & 1);
    int z = 2*z2 + (oct & 1);
    int p = ((b*D1 + x)*H1 + y)*W1 + z;
    const int4* cp = (const int4*)(cnt + (size_t)p*8);
    const int4* up = (const int4*)(cursor + (size_t)p*8);
    int4 c0 = cp[0], c1 = cp[1], u0 = up[0], u1 = up[1];
    cst[t*9 + 0] = (c0.x > 0) ? (u0.x - c0.x) : -1; ccn[t*9 + 0] = (ushort_t)c0.x;
    cst[t*9 + 1] = (c0.y > 0) ? (u0.y - c0.y) : -1; ccn[t*9 + 1] = (ushort_t)c0.y;
    cst[t*9 + 2] = (c0.z > 0) ? (u0.z - c0.z) : -1; ccn[t*9 + 2] = (ushort_t)c0.z;
    cst[t*9 + 3] = (c0.w > 0) ? (u0.w - c0.w) : -1; ccn[t*9 + 3] = (ushort_t)c0.w;
    cst[t*9 + 4] = (c1.x > 0) ? (u1.x - c1.x) : -1; ccn[t*9 + 4] = (ushort_t)c1.x;
    cst[t*9 + 5] = (c1.y > 0) ? (u1.y - c1.y) : -1; ccn[t*9 + 5] = (ushort_t)c1.y;
    cst[t*9 + 6] = (c1.z > 0) ? (u1.z - c1.z) : -1; ccn[t*9 + 6] = (ushort_t)c1.z;
    cst[t*9 + 7] = (c1.w > 0) ? (u1.w - c1.w) : -1; ccn[t*9 + 7] = (ushort_t)c1.w;
    pact[t] = (c0.x + c0.y + c0.z + c0.w + c1.x + c1.y + c1.z + c1.w) > 0 ? 1 : 0;
  }
  __syncthreads();
  int lane = t & 63, wv = t >> 6;
  int l15 = lane & 15, q = lane >> 4;
  int SB = wv * 32;
  v8s a[8][2];
#pragma unroll
  for (int c = 0; c < 8; c++) {
#pragma unroll
    for (int mt = 0; mt < 2; mt++) {
      int site = SB + mt*16 + l15;
      int info = cst[site*9 + c];
      int cn = ccn[site*9 + c];
      uint4 u = make_uint4(0, 0, 0, 0);
      if (info >= 0) {
        u = *(const uint4*)(afb + (size_t)info*32 + q*8);
        if (cn > 1) {   // rare: sum duplicate slots (scaled rows) in f32, repack
          float f0 = b2f((ushort_t)(u.x & 0xffff)), f1 = b2f((ushort_t)(u.x >> 16));
          float f2 = b2f((ushort_t)(u.y & 0xffff)), f3 = b2f((ushort_t)(u.y >> 16));
          float f4 = b2f((ushort_t)(u.z & 0xffff)), f5 = b2f((ushort_t)(u.z >> 16));
          float f6 = b2f((ushort_t)(u.w & 0xffff)), f7 = b2f((ushort_t)(u.w >> 16));
          for (int i = 1; i < cn; i++) {
            uint4 w = *(const uint4*)(afb + (size_t)(info + i)*32 + q*8);
            f0 += b2f((ushort_t)(w.x & 0xffff)); f1 += b2f((ushort_t)(w.x >> 16));
            f2 += b2f((ushort_t)(w.y & 0xffff)); f3 += b2f((ushort_t)(w.y >> 16));
            f4 += b2f((ushort_t)(w.z & 0xffff)); f5 += b2f((ushort_t)(w.z >> 16));
            f6 += b2f((ushort_t)(w.w & 0xffff)); f7 += b2f((ushort_t)(w.w >> 16));
          }
          u.x = (uint_t)f2b(f0) | ((uint_t)f2b(f1) << 16);
          u.y = (uint_t)f2b(f2) | ((uint_t)f2b(f3) << 16);
          u.z = (uint_t)f2b(f4) | ((uint_t)f2b(f5) << 16);
          u.w = (uint_t)f2b(f6) | ((uint_t)f2b(f7) << 16);
        }
      }
      a[c][mt] = *(v8s*)&u;
    }
  }
  v4f acc[2][4];
#pragma unroll
  for (int i = 0; i < 2; i++)
#pragma unroll
    for (int j = 0; j < 4; j++) acc[i][j] = (v4f){0.f, 0.f, 0.f, 0.f};
#pragma unroll
  for (int c = 0; c < 8; c++) {
    v8s b[4];
#pragma unroll
    for (int nt = 0; nt < 4; nt++)
      b[nt] = *(const v8s*)&wlds[c*2048 + (nt*16 + l15)*32 + q*8];
#pragma unroll
    for (int mt = 0; mt < 2; mt++)
#pragma unroll
      for (int nt = 0; nt < 4; nt++)
        acc[mt][nt] = __builtin_amdgcn_mfma_f32_16x16x32_bf16(a[c][mt], b[nt], acc[mt][nt], 0, 0, 0);
  }
  size_t okbase = (size_t)blockIdx.x * 128;
  float ss[4] = {0,0,0,0}, sq[4] = {0,0,0,0};
#pragma unroll
  for (int mt = 0; mt < 2; mt++) {
#pragma unroll
    for (int nt = 0; nt < 4; nt++) {
#pragma unroll
      for (int r = 0; r < 4; r++) {
        int sl = SB + mt*16 + q*4 + r;
        ushort_t h = f2b(acc[mt][nt][r]);
        float v = b2f(h);
        if (pact[sl]) x1b[(okbase + sl)*64 + nt*16 + l15] = h;  // coalesced: consecutive okeys
        ss[nt] += v; sq[nt] += v*v;
      }
    }
  }
  __syncthreads();   // wlds dead -> reuse for stats reduce
  float* redS = (float*)wlds;        // [4][64]
  float* redQ = redS + 256;          // [4][64]
#pragma unroll
  for (int nt = 0; nt < 4; nt++) {
    float v1 = ss[nt], v2 = sq[nt];
    v1 += __shfl_xor(v1, 16); v1 += __shfl_xor(v1, 32);
    v2 += __shfl_xor(v2, 16); v2 += __shfl_xor(v2, 32);
    if (lane < 16) { redS[wv*64 + nt*16 + l15] = v1; redQ[wv*64 + nt*16 + l15] = v2; }
  }
  __syncthreads();
  if (t < 64) {
    float s = redS[t] + redS[64 + t] + redS[128 + t] + redS[192 + t];
    float qq = redQ[t] + redQ[64 + t] + redQ[128 + t] + redQ[192 + t];
    int row = (blockIdx.x & 31) * 80;
    atomicAdd(&sp[row + t], s);
    atomicAdd(&qp[row + t], qq);
  }
}

// ---------------- MFMA conv (conv2/conv3): predicated A-loads on cmask ----------------
template <int CSTRIDE, int CIN_REAL, bool NINT, int NROW, int INSTR,
          int DO, int HO, int WO>
__global__ __launch_bounds__(256) void k_convm(
    const ushort_t* __restrict__ xin, const float* __restrict__ mprev,
    const ushort_t* __restrict__ wtg,
    const float* __restrict__ gam, const float* __restrict__ bet,
    const float* __restrict__ spin, const float* __restrict__ qpin,
    const void* __restrict__ ncnt, const float* __restrict__ npin,
    ushort_t* __restrict__ xout, float* __restrict__ osum, float* __restrict__ osq,
    float* __restrict__ mout, float* __restrict__ npart) {
  const int NCHUNK = CSTRIDE / 4;
  __shared__ __align__(16) float sc[CSTRIDE], sh[CSTRIDE];
  __shared__ float cmask[64*9];
  __shared__ int okl[64];
  __shared__ float redS[4][64], redQ[4][64];
  int t = threadIdx.x;
  if (t < CSTRIDE) {
    float scv = 0.f, shv = 0.f;
    if (t < CIN_REAL) {
      float n;
      if (NINT) n = fmaxf((float)((const int*)ncnt)[0], 1.0f);
      else {
        float nn = 0.f;
        for (int r = 0; r < 32; r++) nn += npin[r];
        n = fmaxf(nn, 1.0f);
      }
      float s1 = 0.f, q1 = 0.f;
      for (int r = 0; r < NROW; r++) { s1 += spin[r*INSTR + t]; q1 += qpin[r*INSTR + t]; }
      float mean = s1 / n;
      float var = q1 / n - mean * mean;
      float s = gam[t] * rsqrtf(var + EPS_);
      scv = s; shv = bet[t] - mean * s;
    }
    sc[t] = scv; sh[t] = shv;
  }
#pragma unroll
  for (int ii = 0; ii < 2; ii++) {
    int idx = t + ii*256;
    cmask[(idx >> 3)*9 + (idx & 7)] = mprev[(size_t)blockIdx.x * 512 + idx];
  }
  if (t < 64) okl[t] = okey<DO,HO,WO>(blockIdx.x * 64 + t);
  __syncthreads();
  int lane = t & 63, wv = t >> 6;
  int l15 = lane & 15, q = lane >> 4;
  int SB = (wv & 1) * 32, NB = (wv >> 1) * 64;
  size_t gbase = (size_t)blockIdx.x * 512;
  v4f acc[2][4];
#pragma unroll
  for (int i = 0; i < 2; i++)
#pragma unroll
    for (int j = 0; j < 4; j++) acc[i][j] = (v4f){0.f, 0.f, 0.f, 0.f};
  uint4 rawN[2]; float mskN[2]; v8s bN[4];
#pragma unroll
  for (int mt = 0; mt < 2; mt++) {
    int site = SB + mt*16 + l15;
    float m = cmask[site*9];
    uint4 rv = make_uint4(0, 0, 0, 0);
    if (m > 0.f) rv = *(const uint4*)(xin + (gbase + site*8) * CSTRIDE + q*8);
    rawN[mt] = rv; mskN[mt] = m;
  }
#pragma unroll
  for (int nt = 0; nt < 4; nt++)
    bN[nt] = *(const v8s*)(wtg + (NB + nt*16 + l15)*32 + q*8);
#pragma unroll
  for (int c = 0; c < NCHUNK; c++) {
    uint4 raw[2] = {rawN[0], rawN[1]};
    float mskc[2] = {mskN[0], mskN[1]};
    v8s b[4] = {bN[0], bN[1], bN[2], bN[3]};
    if (c + 1 < NCHUNK) {
      int ch1 = ((c+1) * 32) / CSTRIDE;
      int cio1 = ((c+1) * 32) % CSTRIDE + q * 8;
#pragma unroll
      for (int mt = 0; mt < 2; mt++) {
        int site = SB + mt*16 + l15;
        float m = cmask[site*9 + ch1];
        uint4 rv = make_uint4(0, 0, 0, 0);
        if (m > 0.f) rv = *(const uint4*)(xin + (gbase + site*8 + ch1) * CSTRIDE + cio1);
        rawN[mt] = rv; mskN[mt] = m;
      }
#pragma unroll
      for (int nt = 0; nt < 4; nt++)
        bN[nt] = *(const v8s*)(wtg + (size_t)(c+1)*4096 + (NB + nt*16 + l15)*32 + q*8);
    }
    int cio = (c * 32) % CSTRIDE + q * 8;
    float4 sc0 = *(const float4*)&sc[cio];
    float4 sc1 = *(const float4*)&sc[cio + 4];
    float4 sh0 = *(const float4*)&sh[cio];
    float4 sh1 = *(const float4*)&sh[cio + 4];
    v8s a[2];
#pragma unroll
    for (int mt = 0; mt < 2; mt++) {
      int4 pk;
      pk.x = (int)bn2(raw[mt].x, sc0.x, sh0.x, sc0.y, sh0.y, mskc[mt]);
      pk.y = (int)bn2(raw[mt].y, sc0.z, sh0.z, sc0.w, sh0.w, mskc[mt]);
      pk.z = (int)bn2(raw[mt].z, sc1.x, sh1.x, sc1.y, sh1.y, mskc[mt]);
      pk.w = (int)bn2(raw[mt].w, sc1.z, sh1.z, sc1.w, sh1.w, mskc[mt]);
      a[mt] = *(v8s*)&pk;
    }
#pragma unroll
    for (int mt = 0; mt < 2; mt++)
#pragma unroll
      for (int nt = 0; nt < 4; nt++)
        acc[mt][nt] = __builtin_amdgcn_mfma_f32_16x16x32_bf16(a[mt], b[nt], acc[mt][nt], 0, 0, 0);
  }
  float ss[4] = {0,0,0,0}, sq[4] = {0,0,0,0};
#pragma unroll
  for (int mt = 0; mt < 2; mt++) {
#pragma unroll
    for (int nt = 0; nt < 4; nt++) {
#pragma unroll
      for (int r = 0; r < 4; r++) {
        int sl = SB + mt*16 + q*4 + r;
        ushort_t h = f2b(acc[mt][nt][r]);
        float v = b2f(h);
        xout[(size_t)okl[sl]*128 + NB + nt*16 + l15] = h;
        ss[nt] += v; sq[nt] += v*v;
      }
    }
  }
  if (t < 64) {
    bool act = false;
#pragma unroll
    for (int ch = 0; ch < 8; ch++) act |= (cmask[t*9 + ch] > 0.f);
    mout[okl[t]] = act ? 1.f : 0.f;
    unsigned long long bal = __ballot(act);
    if (t == 0) atomicAdd(&npart[blockIdx.x & 31], (float)__popcll(bal));
  }
#pragma unroll
  for (int nt = 0; nt < 4; nt++) {
    float v1 = ss[nt], v2 = sq[nt];
    v1 += __shfl_xor(v1, 16); v1 += __shfl_xor(v1, 32);
    v2 += __shfl_xor(v2, 16); v2 += __shfl_xor(v2, 32);
    if (lane < 16) { redS[wv][nt*16 + l15] = v1; redQ[wv][nt*16 + l15] = v2; }
  }
  __syncthreads();
  if (t < 128) {
    float s, qq;
    if (t < 64) { s = redS[0][t] + redS[1][t]; qq = redQ[0][t] + redQ[1][t]; }
    else        { s = redS[2][t-64] + redS[3][t-64]; qq = redQ[2][t-64] + redQ[3][t-64]; }
    int row = (blockIdx.x & 15) * 144;
    atomicAdd(&osum[row + t], s);
    atomicAdd(&osq[row + t], qq);
  }
}

// ---------------- final conv + sigmoid + mask ----------------
__global__ __launch_bounds__(256) void k_final(
    const ushort_t* __restrict__ x3b, const float* __restrict__ m3b,
    const float* __restrict__ w4, const float* __restrict__ gam,
    const float* __restrict__ bet, const float* __restrict__ spin,
    const float* __restrict__ qpin, const float* __restrict__ npin,
    float* __restrict__ out) {
  __shared__ float sc[128], sh[128];
  __shared__ float msk[8];
  __shared__ float red[256];
  int t = threadIdx.x;
  if (t < 128) {
    float nn = 0.f;
    for (int r = 0; r < 32; r++) nn += npin[r];
    float n = fmaxf(nn, 1.0f);
    float s1 = 0.f, q1 = 0.f;
    for (int r = 0; r < 16; r++) { s1 += spin[r*144 + t]; q1 += qpin[r*144 + t]; }
    float mean = s1 / n;
    float var = q1 / n - mean * mean;
    float s = gam[t] * rsqrtf(var + EPS_);
    sc[t] = s; sh[t] = bet[t] - mean * s;
  }
  int g = blockIdx.x;
  if (t < 8) msk[t] = m3b[g*8 + t];
  __syncthreads();
  float acc = 0.f;
#pragma unroll
  for (int ii = 0; ii < 4; ii++) {
    int k = t + ii*256;
    int ch = k >> 7, ci = k & 127;
    float v = b2f(x3b[(size_t)(g*8 + ch)*128 + ci]);
    v = v * sc[ci] + sh[ci];
    v = (v > 0.f ? v : LEAK_ * v) * msk[ch];
    acc += v * w4[k];
  }
  red[t] = acc;
  __syncthreads();
  if (t < 128) red[t] += red[t + 128];
  __syncthreads();
  if (t < 64) {
    float v = red[t] + red[t + 64];
#pragma unroll
    for (int off = 32; off > 0; off >>= 1) v += __shfl_down(v, off);
    if (t == 0) {
      float any = (msk[0] + msk[1] + msk[2] + msk[3] + msk[4] + msk[5] + msk[6] + msk[7]) > 0.f ? 1.f : 0.f;
      out[g] = any / (1.0f + expf(-v));
    }
  }
}

extern "C" void kernel_launch(void* const* d_in, const int* in_sizes, int n_in,
                              void* d_out, int out_size, void* d_ws, size_t ws_size,
                              hipStream_t stream) {
  (void)in_sizes; (void)n_in; (void)out_size; (void)ws_size;
  const float* feat = (const float*)d_in[0];
  const int*   crd  = (const int*)d_in[1];
  const float* w1 = (const float*)d_in[2];
  const float* g1 = (const float*)d_in[3];
  const float* b1 = (const float*)d_in[4];
  const float* w2 = (const float*)d_in[5];
  const float* g2 = (const float*)d_in[6];
  const float* b2 = (const float*)d_in[7];
  const float* w3 = (const float*)d_in[8];
  const float* g3 = (const float*)d_in[9];
  const float* b3 = (const float*)d_in[10];
  const float* w4 = (const float*)d_in[11];
  float* out = (float*)d_out;
  float* ws  = (float*)d_ws;

  int*      cnt    = (int*)(ws + OFF_CNT);
  float*    st     = ws + OFF_STATS;
  int*      cursor = (int*)(ws + OFF_CURSOR);
  ushort_t* wt1g   = (ushort_t*)(ws + OFF_WT1);
  ushort_t* wt2g   = (ushort_t*)(ws + OFF_WT2);
  ushort_t* wt3g   = (ushort_t*)(ws + OFF_WT3);
  ushort_t* afb    = (ushort_t*)(ws + OFF_AFEATB);
  ushort_t* x1b    = (ushort_t*)(ws + OFF_X1B);
  ushort_t* x2b    = (ushort_t*)(ws + OFF_X2B);
  ushort_t* x3b    = (ushort_t*)(ws + OFF_X3B);
  float*    m1b    = ws + OFF_M1;
  float*    m2b    = ws + OFF_M2;
  float*    m3b    = ws + OFF_M3;
  int*      nactp  = (int*)(st + ST_PK);

  hipMemsetAsync(cnt, 0, (size_t)NVOX * sizeof(int), stream);

  k_front<<<NB_COUNT + NB_PREPW + NB_STZ, 256, 0, stream>>>(
      crd, cnt, w1, w2, w3, wt1g, wt2g, wt3g, st);
  k_alloc<<<NVOX / 16384, 1024, 0, stream>>>(cnt, cursor, m1b,
                                             (int*)(st + ST_GCUR), nactp);
  k_scatter<<<(PNUM + 255) / 256, 256, 0, stream>>>(crd, feat, cnt, cursor, afb);
  k_conv1m<<<N1S / 128, 256, 0, stream>>>(afb, cnt, cursor, wt1g, x1b,
                                          st + ST_S1P, st + ST_Q1P);
  k_convm<64, 64, true, 32, 80, D2,H2,W2><<<N2S / 64, 256, 0, stream>>>(
      x1b, m1b, wt2g, g1, b1, st + ST_S1P, st + ST_Q1P, (const void*)nactp, nullptr,
      x2b, st + ST_S2P, st + ST_Q2P, m2b, st + ST_N2P);
  k_convm<128, 96, false, 16, 144, D3,H3,W3><<<N3S / 64, 256, 0, stream>>>(
      x2b, m2b, wt3g, g2, b2, st + ST_S2P, st + ST_Q2P, nullptr, st + ST_N2P,
      x3b, st + ST_S3P, st + ST_Q3P, m3b, st + ST_N3P);
  k_final<<<N4S, 256, 0, stream>>>(x3b, m3b, w4, g3, b3,
                                   st + ST_S3P, st + ST_Q3P, st + ST_N3P, out);
}